// Round 9
// baseline (264.982 us; speedup 1.0000x reference)
//
#include <hip/hip_runtime.h>
#include <hip/hip_bf16.h>

typedef __attribute__((ext_vector_type(4))) float f32x4;
typedef __attribute__((ext_vector_type(8))) short s16x8;
typedef __attribute__((ext_vector_type(4))) short s16x4;

__device__ __forceinline__ float fexp2(float x) {   // 2^x (hw interlocked on CDNA)
    float y; asm("v_exp_f32 %0, %1" : "=v"(y) : "v"(x)); return y;
}

// ---------------- RoPE tables (tiny, double precision) ----------------
__global__ void rope_tables(float* __restrict__ cosT, float* __restrict__ sinT) {
    const int s = blockIdx.x, j = threadIdx.x;          // s in [0,2048), j in [0,64)
    const double inv = pow(10000.0, -(double)j / 64.0);
    const double f = (double)s * inv;
    cosT[s * 64 + j] = (float)cos(f);
    sinT[s * 64 + j] = (float)sin(f);
}

// ---------------- mask -> additive float bias ----------------
__global__ void mask_bias(const int* __restrict__ mask, float* __restrict__ mb, int n) {
    const int i = blockIdx.x * 256 + threadIdx.x;
    if (i < n) mb[i] = (mask[i] == 0) ? -1e30f : 0.f;
}

// ---------------- cast fp32 -> bf16 (vectorized) ----------------
__global__ __launch_bounds__(256)
void cast_f32_bf16(const float* __restrict__ src, __hip_bfloat16* __restrict__ dst, int n4) {
    const int i = blockIdx.x * 256 + threadIdx.x;
    if (i < n4) {
        f32x4 v = *reinterpret_cast<const f32x4*>(src + (size_t)i * 4);
        union { s16x4 v4; __hip_bfloat16 h[4]; } u;
#pragma unroll
        for (int j = 0; j < 4; ++j) u.h[j] = __float2bfloat16(v[j]);
        *reinterpret_cast<s16x4*>(dst + (size_t)i * 4) = u.v4;
    }
}

// ---------------- tiled transpose + cast: dst[c][r] = (bf16)src[r][c] ----------------
__global__ __launch_bounds__(256)
void transpose_cast(const float* __restrict__ src, __hip_bfloat16* __restrict__ dst,
                    int R, int C) {
    __shared__ __align__(16) float t[32][33];
    const int tx = threadIdx.x, ty = threadIdx.y;       // (32, 8)
    const int r0 = blockIdx.y * 32, c0 = blockIdx.x * 32;
#pragma unroll
    for (int i = 0; i < 32; i += 8)
        t[ty + i][tx] = src[(size_t)(r0 + ty + i) * C + c0 + tx];
    __syncthreads();
#pragma unroll
    for (int i = 0; i < 32; i += 8)
        dst[(size_t)(c0 + ty + i) * R + r0 + tx] = __float2bfloat16(t[tx][ty + i]);
}

// ---------------- V slice of qkv -> Vt[b][hh][d][s] (LDS-tiled transpose) ----------------
__global__ __launch_bounds__(256)
void vt_transpose(const float* __restrict__ qkv, __hip_bfloat16* __restrict__ Vt) {
    __shared__ __align__(16) float t[32][33];
    const int tx = threadIdx.x, ty = threadIdx.y;       // (32, 8)
    const int s0 = blockIdx.x * 32, d0 = blockIdx.y * 32;
    const int bh = blockIdx.z, b = bh >> 2, hh = bh & 3;
#pragma unroll
    for (int i = 0; i < 32; i += 8)
        t[ty + i][tx] = qkv[(size_t)(b * 2048 + s0 + ty + i) * 3072 + 2560 + hh * 128 + d0 + tx];
    __syncthreads();
#pragma unroll
    for (int i = 0; i < 32; i += 8)
        Vt[((size_t)(bh * 128) + d0 + ty + i) * 2048 + s0 + tx] = __float2bfloat16(t[tx][ty + i]);
}

// ---------------- 256-row-tile GEMM with counted-vmcnt 4-slot pipeline (T4) ----------
// LDS = 128 KiB -> hard cap of 1 block/CU; declare (512,1) so the register
// allocator gets the full 256 V+A budget (acc[8][NI] alone is 32*NI regs).
template<int NI>   // NI = per-wave N fragments: 4 -> BN=256, 2 -> BN=128
__global__ __launch_bounds__(512, 1)
void gemm256_bt_f32(const __hip_bfloat16* __restrict__ A,
                    const __hip_bfloat16* __restrict__ Bt,
                    float* __restrict__ C, int M, int N, int K) {
    constexpr int NB = NI / 2;                          // B-stage loads per thread
    __shared__ __align__(16) __hip_bfloat16 sm[4][2][8192];
    const int tid = threadIdx.x;
    const int l = tid & 63, w = tid >> 6;               // 8 waves
    const int lo = l & 15, hi = l >> 4;
    const int wm = w >> 2, wn = w & 3;
    const int row0 = blockIdx.y * 256;
    const int col0 = blockIdx.x * (NI * 64);
    const int nk = K >> 5;

    f32x4 acc[8][NI];
#pragma unroll
    for (int mi = 0; mi < 8; ++mi)
#pragma unroll
        for (int ni = 0; ni < NI; ++ni) acc[mi][ni] = f32x4{0.f, 0.f, 0.f, 0.f};

    auto stage = [&](int kt) {
        const int s = kt & 3, k0 = kt << 5;
#pragma unroll
        for (int i = 0; i < 2; ++i) {                   // A: 256 rows x 4 chunks
            const int c = i * 512 + tid;
            const int r = c >> 2, sw = ((c & 3) ^ (r & 3)) * 8;
            __builtin_amdgcn_global_load_lds(
                (const __attribute__((address_space(1))) void*)(A + (size_t)(row0 + r) * K + k0 + sw),
                (__attribute__((address_space(3))) void*)(&sm[s][0][c * 8]), 16, 0, 0);
        }
#pragma unroll
        for (int i = 0; i < NB; ++i) {                  // B: NI*64 rows x 4 chunks
            const int c = i * 512 + tid;
            const int r = c >> 2, sw = ((c & 3) ^ (r & 3)) * 8;
            __builtin_amdgcn_global_load_lds(
                (const __attribute__((address_space(1))) void*)(Bt + (size_t)(col0 + r) * K + k0 + sw),
                (__attribute__((address_space(3))) void*)(&sm[s][1][c * 8]), 16, 0, 0);
        }
    };

    stage(0); stage(1); stage(2);                       // 3 tiles ahead
    for (int kt = 0; kt < nk; ++kt) {
        const int s = kt & 3;
        if (kt < nk - 2) {
            if constexpr (NI == 4) asm volatile("s_waitcnt vmcnt(8)" ::: "memory");
            else                   asm volatile("s_waitcnt vmcnt(6)" ::: "memory");
        } else if (kt == nk - 2) {
            if constexpr (NI == 4) asm volatile("s_waitcnt vmcnt(4)" ::: "memory");
            else                   asm volatile("s_waitcnt vmcnt(3)" ::: "memory");
        } else {
            asm volatile("s_waitcnt vmcnt(0)" ::: "memory");
        }
        asm volatile("s_waitcnt lgkmcnt(0)" ::: "memory");  // slot reads of kt-1 done
        asm volatile("s_barrier" ::: "memory");             // no compiler drain added
        if (kt + 3 < nk) stage(kt + 3);                     // into slot (kt-1)&3: safe

        s16x8 af[8], bf[NI];
#pragma unroll
        for (int mi = 0; mi < 8; ++mi)
            af[mi] = *reinterpret_cast<const s16x8*>(
                &sm[s][0][(wm * 128 + mi * 16 + lo) * 32 + ((hi ^ (lo & 3)) * 8)]);
#pragma unroll
        for (int ni = 0; ni < NI; ++ni)
            bf[ni] = *reinterpret_cast<const s16x8*>(
                &sm[s][1][(wn * NI * 16 + ni * 16 + lo) * 32 + ((hi ^ (lo & 3)) * 8)]);
        __builtin_amdgcn_s_setprio(1);
#pragma unroll
        for (int mi = 0; mi < 8; ++mi)
#pragma unroll
            for (int ni = 0; ni < NI; ++ni)
                acc[mi][ni] = __builtin_amdgcn_mfma_f32_16x16x32_bf16(af[mi], bf[ni], acc[mi][ni], 0, 0, 0);
        __builtin_amdgcn_s_setprio(0);
    }
    const int rbase = row0 + wm * 128 + hi * 4;
    const int cbase = col0 + wn * NI * 16 + lo;
#pragma unroll
    for (int mi = 0; mi < 8; ++mi)
#pragma unroll
        for (int ni = 0; ni < NI; ++ni)
#pragma unroll
            for (int r = 0; r < 4; ++r)
                C[(size_t)(rbase + mi * 16 + r) * N + cbase + ni * 16] = acc[mi][ni][r];
}

// ---------------- RoPE + scatter (Q/K only, float4-vectorized) ----------------
__global__ __launch_bounds__(256)
void rope_scatter(const float* __restrict__ qkv,
                  const float* __restrict__ cosT, const float* __restrict__ sinT,
                  __hip_bfloat16* __restrict__ Qr, __hip_bfloat16* __restrict__ Kr) {
    const int m = blockIdx.y;                           // token row, 0..4095
    const int col4 = blockIdx.x * 256 + threadIdx.x;    // 0..639
    if (col4 >= 640) return;
    const int col = col4 * 4;
    const int b = m >> 11, s = m & 2047;
    const int d = col & 127;                            // 4-aligned
    const int j = d & 63;
    const f32x4 v = *reinterpret_cast<const f32x4*>(qkv + (size_t)m * 3072 + col);
    const f32x4 p = *reinterpret_cast<const f32x4*>(qkv + (size_t)m * 3072 + (col ^ 64));
    const f32x4 c4 = *reinterpret_cast<const f32x4*>(cosT + s * 64 + j);
    const f32x4 s4 = *reinterpret_cast<const f32x4*>(sinT + s * 64 + j);
    const float sgn = (d < 64) ? -1.f : 1.f;
    union { s16x4 v4; __hip_bfloat16 h[4]; } u;
#pragma unroll
    for (int i = 0; i < 4; ++i)
        u.h[i] = __float2bfloat16(v[i] * c4[i] + sgn * p[i] * s4[i]);
    if (col < 2048) {
        const int hh = col >> 7;
        *reinterpret_cast<s16x4*>(&Qr[((size_t)(b * 16 + hh) * 2048 + s) * 128 + d]) = u.v4;
    } else {
        const int hh = (col - 2048) >> 7;
        *reinterpret_cast<s16x4*>(&Kr[((size_t)(b * 4 + hh) * 2048 + s) * 128 + d]) = u.v4;
    }
}

// ---------------- flash attention: 128 Q-rows/block (8 waves), KV tiles of 64 ----------------
// Swapped QK^T (T12) + in-register exp2-domain softmax + defer-max (T13) +
// double-buffered K/V with ONE barrier per tile; x2 unroll for static LDS bases.
// LDS 80KB caps at 2 blocks/CU -> declare (512,2) so the wave gets 128 VGPRs
// (the (512,4) variant forced 64 VGPR: remat/spill with zero occupancy gain).
// Mask bias loads issued BEFORE the K/V prefetch so the post-QK fmaf waits
// vmcnt(8), not vmcnt(0) -> prefetch stays in flight across the tile (T14).
__global__ __launch_bounds__(512, 2)
void attn_kernel(const __hip_bfloat16* __restrict__ Qr,
                 const __hip_bfloat16* __restrict__ Kr,
                 const __hip_bfloat16* __restrict__ Vt,
                 const float* __restrict__ maskb,
                 __hip_bfloat16* __restrict__ Oo) {
    const int S = 2048;
    const int qt = blockIdx.x;                          // 0..15 (128 q-rows per block)
    const int bh = blockIdx.y;                          // 0..31
    const int b = bh >> 4, h = bh & 15, kvh = h >> 2;
    const int tid = threadIdx.x;
    const int l = tid & 63, w = tid >> 6;               // 8 waves
    const int lo = l & 15, hi = l >> 4;
    __shared__ __align__(16) __hip_bfloat16 Ks[2][64 * 128];   // [kv][d], swizzled
    __shared__ __align__(16) __hip_bfloat16 Vs[2][128 * 64];   // [d][kv], swizzled
    __shared__ __align__(16) __hip_bfloat16 Ps[8][16 * 64];    // per-wave [q][kv], swizzled

    const __hip_bfloat16* Qb = Qr + (size_t)(b * 16 + h) * S * 128;
    const __hip_bfloat16* Kb = Kr + (size_t)(b * 4 + kvh) * S * 128;
    const __hip_bfloat16* Vb = Vt + (size_t)(b * 4 + kvh) * 128 * S;
    const float* mrow = maskb + b * S;

    // Q fragments in registers: wave owns rows qt*128 + w*16 .. +15
    const int qrow = qt * 128 + w * 16 + lo;
    s16x8 qf[4];
#pragma unroll
    for (int kc = 0; kc < 4; ++kc)
        qf[kc] = *reinterpret_cast<const s16x8*>(Qb + (size_t)qrow * 128 + kc * 32 + hi * 8);

    float m_run = -1e30f, l_run = 0.f;                  // exp2-domain; lane's q-row = lo
    f32x4 o[8];
#pragma unroll
    for (int n = 0; n < 8; ++n) o[n] = f32x4{0.f, 0.f, 0.f, 0.f};
    const float scale2 = 0.12751682f;                   // 1/sqrt(128) * log2(e)

    // --- staging geometry ---
    const int krow = tid >> 4, kc8 = tid & 15;          // krow 0..31 (+i*32)
    const int koff = (kc8 ^ (krow & 7)) * 8;
    const int vrow = tid >> 3, vc8 = tid & 7;           // vrow 0..63 (+i*64)
    const int voff = (vc8 ^ (vrow & 7)) * 8;

    s16x8 kreg[2], vreg[2];
    auto load_tile = [&](int kv0) {
#pragma unroll
        for (int i = 0; i < 2; ++i)
            kreg[i] = *reinterpret_cast<const s16x8*>(
                Kb + (size_t)(kv0 + i * 32 + krow) * 128 + kc8 * 8);
#pragma unroll
        for (int i = 0; i < 2; ++i)
            vreg[i] = *reinterpret_cast<const s16x8*>(
                Vb + (size_t)(i * 64 + vrow) * S + kv0 + vc8 * 8);
    };

    auto body = [&](int kt, __hip_bfloat16* Kc, __hip_bfloat16* Vc) {
        const int kv0 = kt * 64;
        // mask bias FIRST (so later use waits vmcnt(8), keeping prefetch in flight)
        f32x4 bi[4];
#pragma unroll
        for (int ksub = 0; ksub < 4; ++ksub)
            bi[ksub] = *reinterpret_cast<const f32x4*>(mrow + kv0 + ksub * 16 + hi * 4);
#pragma unroll
        for (int i = 0; i < 2; ++i)
            *reinterpret_cast<s16x8*>(Kc + (i * 32 + krow) * 128 + koff) = kreg[i];
#pragma unroll
        for (int i = 0; i < 2; ++i)
            *reinterpret_cast<s16x8*>(Vc + (i * 64 + vrow) * 64 + voff) = vreg[i];
        if (kt < 31) load_tile(kv0 + 64);               // lands under compute (T14)
        __syncthreads();                                // buf ready for all

        // P^T = (K Q^T): lane holds P[kv=ksub*16+hi*4+r][q=lo]
        f32x4 sc[4] = {};
        __builtin_amdgcn_s_setprio(1);
#pragma unroll
        for (int ksub = 0; ksub < 4; ++ksub) {
            const int kr = ksub * 16 + lo;
            const int ksw = kr & 7;
#pragma unroll
            for (int kc = 0; kc < 4; ++kc) {
                s16x8 kf = *reinterpret_cast<const s16x8*>(
                    Kc + kr * 128 + (((kc * 4 + hi) ^ ksw) * 8));
                sc[ksub] = __builtin_amdgcn_mfma_f32_16x16x32_bf16(kf, qf[kc], sc[ksub], 0, 0, 0);
            }
        }
        __builtin_amdgcn_s_setprio(0);
        // scale (log2-domain) + additive mask bias
#pragma unroll
        for (int ksub = 0; ksub < 4; ++ksub)
#pragma unroll
            for (int r = 0; r < 4; ++r)
                sc[ksub][r] = fmaf(sc[ksub][r], scale2, bi[ksub][r]);
        // tile row-max
        float a0 = fmaxf(fmaxf(sc[0][0], sc[0][1]), fmaxf(sc[0][2], sc[0][3]));
        float a1 = fmaxf(fmaxf(sc[1][0], sc[1][1]), fmaxf(sc[1][2], sc[1][3]));
        float a2 = fmaxf(fmaxf(sc[2][0], sc[2][1]), fmaxf(sc[2][2], sc[2][3]));
        float a3 = fmaxf(fmaxf(sc[3][0], sc[3][1]), fmaxf(sc[3][2], sc[3][3]));
        float mx = fmaxf(fmaxf(a0, a1), fmaxf(a2, a3));
        mx = fmaxf(mx, __shfl_xor(mx, 16));
        mx = fmaxf(mx, __shfl_xor(mx, 32));
        // defer-max: only rescale when some row's max grew past 8*log2e
        if (__ballot(mx > m_run + 11.5417f) != 0ull) {
            const float mnew = fmaxf(m_run, mx);
            const float alpha = fexp2(m_run - mnew);
            m_run = mnew;
            l_run *= alpha;
            float ar[4];
#pragma unroll
            for (int r = 0; r < 4; ++r) ar[r] = __shfl(alpha, hi * 4 + r);
#pragma unroll
            for (int n = 0; n < 8; ++n)
#pragma unroll
                for (int r = 0; r < 4; ++r) o[n][r] *= ar[r];
        }
        // exp2 + row-sum (P bounded by 2^11.54 = e^8 under defer)
        float s0 = 0.f, s1 = 0.f, s2 = 0.f, s3 = 0.f;
#pragma unroll
        for (int r = 0; r < 4; ++r) {
            sc[0][r] = fexp2(sc[0][r] - m_run); s0 += sc[0][r];
            sc[1][r] = fexp2(sc[1][r] - m_run); s1 += sc[1][r];
            sc[2][r] = fexp2(sc[2][r] - m_run); s2 += sc[2][r];
            sc[3][r] = fexp2(sc[3][r] - m_run); s3 += sc[3][r];
        }
        float ssum = (s0 + s1) + (s2 + s3);
        ssum += __shfl_xor(ssum, 16);
        ssum += __shfl_xor(ssum, 32);
        l_run += ssum;
        // P -> LDS: cvt_pk pairs, one b64 per ksub (row q=lo, cols ksub*16+hi*4..+3)
        __hip_bfloat16* pb = &Ps[w][0];
#pragma unroll
        for (int ksub = 0; ksub < 4; ++ksub) {
            unsigned int d0, d1;
            asm("v_cvt_pk_bf16_f32 %0, %1, %2" : "=v"(d0) : "v"(sc[ksub][0]), "v"(sc[ksub][1]));
            asm("v_cvt_pk_bf16_f32 %0, %1, %2" : "=v"(d1) : "v"(sc[ksub][2]), "v"(sc[ksub][3]));
            const int byteoff = lo * 128 + (((ksub * 2 + (hi >> 1)) ^ (lo & 7)) * 16) + (hi & 1) * 8;
            uint2 dd; dd.x = d0; dd.y = d1;
            *reinterpret_cast<uint2*>(reinterpret_cast<char*>(pb) + byteoff) = dd;
        }
        // O += P V
        __builtin_amdgcn_s_setprio(1);
#pragma unroll
        for (int kg = 0; kg < 2; ++kg) {
            s16x8 pa = *reinterpret_cast<const s16x8*>(
                pb + lo * 64 + (((kg * 4 + hi) ^ (lo & 7)) * 8));
#pragma unroll
            for (int n = 0; n < 8; ++n) {
                const int vr = n * 16 + lo;
                s16x8 vb = *reinterpret_cast<const s16x8*>(
                    Vc + vr * 64 + (((kg * 4 + hi) ^ (vr & 7)) * 8));
                o[n] = __builtin_amdgcn_mfma_f32_16x16x32_bf16(pa, vb, o[n], 0, 0, 0);
            }
        }
        __builtin_amdgcn_s_setprio(0);
        // no trailing barrier: next call writes the other buffer
    };

    load_tile(0);
    for (int kt2 = 0; kt2 < 16; ++kt2) {                // x2 unroll: static LDS bases
        body(2 * kt2,     &Ks[0][0], &Vs[0][0]);
        body(2 * kt2 + 1, &Ks[1][0], &Vs[1][0]);
    }
    // epilogue: attn_out[b*S+s][h*128+d] = o / l   (l lives at lane q)
    float lr[4];
#pragma unroll
    for (int r = 0; r < 4; ++r) lr[r] = __shfl(l_run, hi * 4 + r);
    const int orow = b * S + qt * 128 + w * 16 + (hi * 4);
    const int ocol = h * 128 + lo;
#pragma unroll
    for (int n = 0; n < 8; ++n)
#pragma unroll
        for (int r = 0; r < 4; ++r)
            Oo[(size_t)(orow + r) * 2048 + ocol + n * 16] = __float2bfloat16(o[n][r] / lr[r]);
}

// ---------------- host launch ----------------
extern "C" void kernel_launch(void* const* d_in, const int* in_sizes, int n_in,
                              void* d_out, int out_size, void* d_ws, size_t ws_size,
                              hipStream_t stream) {
    const float* x  = (const float*)d_in[0];
    const int* mask = (const int*)d_in[1];
    const float* Wq = (const float*)d_in[2];
    const float* Wk = (const float*)d_in[3];
    const float* Wv = (const float*)d_in[4];
    const float* Wo = (const float*)d_in[5];
    float* out = (float*)d_out;

    char* ws = (char*)d_ws;
    size_t off = 0;
    auto alloc = [&](size_t bytes) -> void* {
        void* p = ws + off;
        off += (bytes + 255) & ~(size_t)255;
        return p;
    };
    __hip_bfloat16* xb     = (__hip_bfloat16*)alloc(4096ULL * 2048 * 2);   // 16 MB
    __hip_bfloat16* wqkv_t = (__hip_bfloat16*)alloc(3072ULL * 2048 * 2);   // 12 MB
    __hip_bfloat16* wo_t   = (__hip_bfloat16*)alloc(2048ULL * 2048 * 2);   // 8 MB
    float*          qkv    = (float*)alloc(4096ULL * 3072 * 4);            // 48 MB
    __hip_bfloat16* Kr     = (__hip_bfloat16*)alloc(2ULL * 4 * 2048 * 128 * 2);  // 4 MB
    __hip_bfloat16* Vt     = (__hip_bfloat16*)alloc(2ULL * 4 * 2048 * 128 * 2);  // 4 MB
    float*          cosT   = (float*)alloc(2048ULL * 64 * 4);
    float*          sinT   = (float*)alloc(2048ULL * 64 * 4);
    float*          maskb  = (float*)alloc(2ULL * 2048 * 4);
    // Aliases (regions dead by the time these are written):
    __hip_bfloat16* Qr    = xb;                   // xb dead after QKV GEMM; Qr written after
    __hip_bfloat16* attno = (__hip_bfloat16*)qkv; // qkv dead after rope/vt; attno written after

    rope_tables<<<dim3(2048), dim3(64), 0, stream>>>(cosT, sinT);
    mask_bias<<<dim3(16), dim3(256), 0, stream>>>(mask, maskb, 4096);
    cast_f32_bf16<<<dim3(8192), dim3(256), 0, stream>>>(x, xb, 2097152);
    transpose_cast<<<dim3(64, 64), dim3(32, 8), 0, stream>>>(Wq, wqkv_t, 2048, 2048);
    transpose_cast<<<dim3(16, 64), dim3(32, 8), 0, stream>>>(Wk, wqkv_t + 2048ULL * 2048, 2048, 512);
    transpose_cast<<<dim3(16, 64), dim3(32, 8), 0, stream>>>(Wv, wqkv_t + 2560ULL * 2048, 2048, 512);
    transpose_cast<<<dim3(64, 64), dim3(32, 8), 0, stream>>>(Wo, wo_t, 2048, 2048);

    // QKV: 256x256 tiles -> grid (12,16)
    gemm256_bt_f32<4><<<dim3(12, 16), dim3(512), 0, stream>>>(xb, wqkv_t, qkv, 4096, 3072, 2048);
    rope_scatter<<<dim3(3, 4096), dim3(256), 0, stream>>>(qkv, cosT, sinT, Qr, Kr);
    vt_transpose<<<dim3(64, 4, 8), dim3(32, 8), 0, stream>>>(qkv, Vt);
    attn_kernel<<<dim3(16, 32), dim3(512), 0, stream>>>(Qr, Kr, Vt, maskb, attno);
    // Wo: 256x128 tiles -> grid (16,16) = 256 blocks (full chip)
    gemm256_bt_f32<2><<<dim3(16, 16), dim3(512), 0, stream>>>(attno, wo_t, out, 4096, 2048, 2048);
}

// Round 10
// 251.018 us; speedup vs baseline: 1.0556x; 1.0556x over previous
//
#include <hip/hip_runtime.h>
#include <hip/hip_bf16.h>

typedef __attribute__((ext_vector_type(4))) float f32x4;
typedef __attribute__((ext_vector_type(8))) short s16x8;
typedef __attribute__((ext_vector_type(4))) short s16x4;

__device__ __forceinline__ float fexp2(float x) {   // 2^x (hw interlocked on CDNA)
    float y; asm("v_exp_f32 %0, %1" : "=v"(y) : "v"(x)); return y;
}

// ---------------- RoPE tables (tiny, double precision) ----------------
__global__ void rope_tables(float* __restrict__ cosT, float* __restrict__ sinT) {
    const int s = blockIdx.x, j = threadIdx.x;          // s in [0,2048), j in [0,64)
    const double inv = pow(10000.0, -(double)j / 64.0);
    const double f = (double)s * inv;
    cosT[s * 64 + j] = (float)cos(f);
    sinT[s * 64 + j] = (float)sin(f);
}

// ---------------- mask -> additive float bias ----------------
__global__ void mask_bias(const int* __restrict__ mask, float* __restrict__ mb, int n) {
    const int i = blockIdx.x * 256 + threadIdx.x;
    if (i < n) mb[i] = (mask[i] == 0) ? -1e30f : 0.f;
}

// ---------------- cast fp32 -> bf16 (vectorized) ----------------
__global__ __launch_bounds__(256)
void cast_f32_bf16(const float* __restrict__ src, __hip_bfloat16* __restrict__ dst, int n4) {
    const int i = blockIdx.x * 256 + threadIdx.x;
    if (i < n4) {
        f32x4 v = *reinterpret_cast<const f32x4*>(src + (size_t)i * 4);
        union { s16x4 v4; __hip_bfloat16 h[4]; } u;
#pragma unroll
        for (int j = 0; j < 4; ++j) u.h[j] = __float2bfloat16(v[j]);
        *reinterpret_cast<s16x4*>(dst + (size_t)i * 4) = u.v4;
    }
}

// ---------------- tiled transpose + cast: dst[c][r] = (bf16)src[r][c] ----------------
__global__ __launch_bounds__(256)
void transpose_cast(const float* __restrict__ src, __hip_bfloat16* __restrict__ dst,
                    int R, int C) {
    __shared__ __align__(16) float t[32][33];
    const int tx = threadIdx.x, ty = threadIdx.y;       // (32, 8)
    const int r0 = blockIdx.y * 32, c0 = blockIdx.x * 32;
#pragma unroll
    for (int i = 0; i < 32; i += 8)
        t[ty + i][tx] = src[(size_t)(r0 + ty + i) * C + c0 + tx];
    __syncthreads();
#pragma unroll
    for (int i = 0; i < 32; i += 8)
        dst[(size_t)(c0 + ty + i) * R + r0 + tx] = __float2bfloat16(t[tx][ty + i]);
}

// ---------------- V slice of qkv -> Vt[b][hh][d][s] (LDS-tiled transpose) ----------------
__global__ __launch_bounds__(256)
void vt_transpose(const float* __restrict__ qkv, __hip_bfloat16* __restrict__ Vt) {
    __shared__ __align__(16) float t[32][33];
    const int tx = threadIdx.x, ty = threadIdx.y;       // (32, 8)
    const int s0 = blockIdx.x * 32, d0 = blockIdx.y * 32;
    const int bh = blockIdx.z, b = bh >> 2, hh = bh & 3;
#pragma unroll
    for (int i = 0; i < 32; i += 8)
        t[ty + i][tx] = qkv[(size_t)(b * 2048 + s0 + ty + i) * 3072 + 2560 + hh * 128 + d0 + tx];
    __syncthreads();
#pragma unroll
    for (int i = 0; i < 32; i += 8)
        Vt[((size_t)(bh * 128) + d0 + ty + i) * 2048 + s0 + tx] = __float2bfloat16(t[tx][ty + i]);
}

// ---------------- 256-row-tile GEMM with counted-vmcnt 4-slot pipeline (T4) ----------
// LDS = 128 KiB -> hard cap of 1 block/CU; (512,1) gives the register
// allocator the full budget (acc[8][NI] alone is 32*NI regs).
template<int NI>   // NI = per-wave N fragments: 4 -> BN=256, 2 -> BN=128
__global__ __launch_bounds__(512, 1)
void gemm256_bt_f32(const __hip_bfloat16* __restrict__ A,
                    const __hip_bfloat16* __restrict__ Bt,
                    float* __restrict__ C, int M, int N, int K) {
    constexpr int NB = NI / 2;                          // B-stage loads per thread
    __shared__ __align__(16) __hip_bfloat16 sm[4][2][8192];
    const int tid = threadIdx.x;
    const int l = tid & 63, w = tid >> 6;               // 8 waves
    const int lo = l & 15, hi = l >> 4;
    const int wm = w >> 2, wn = w & 3;
    const int row0 = blockIdx.y * 256;
    const int col0 = blockIdx.x * (NI * 64);
    const int nk = K >> 5;

    f32x4 acc[8][NI];
#pragma unroll
    for (int mi = 0; mi < 8; ++mi)
#pragma unroll
        for (int ni = 0; ni < NI; ++ni) acc[mi][ni] = f32x4{0.f, 0.f, 0.f, 0.f};

    auto stage = [&](int kt) {
        const int s = kt & 3, k0 = kt << 5;
#pragma unroll
        for (int i = 0; i < 2; ++i) {                   // A: 256 rows x 4 chunks
            const int c = i * 512 + tid;
            const int r = c >> 2, sw = ((c & 3) ^ (r & 3)) * 8;
            __builtin_amdgcn_global_load_lds(
                (const __attribute__((address_space(1))) void*)(A + (size_t)(row0 + r) * K + k0 + sw),
                (__attribute__((address_space(3))) void*)(&sm[s][0][c * 8]), 16, 0, 0);
        }
#pragma unroll
        for (int i = 0; i < NB; ++i) {                  // B: NI*64 rows x 4 chunks
            const int c = i * 512 + tid;
            const int r = c >> 2, sw = ((c & 3) ^ (r & 3)) * 8;
            __builtin_amdgcn_global_load_lds(
                (const __attribute__((address_space(1))) void*)(Bt + (size_t)(col0 + r) * K + k0 + sw),
                (__attribute__((address_space(3))) void*)(&sm[s][1][c * 8]), 16, 0, 0);
        }
    };

    stage(0); stage(1); stage(2);                       // 3 tiles ahead
    for (int kt = 0; kt < nk; ++kt) {
        const int s = kt & 3;
        if (kt < nk - 2) {
            if constexpr (NI == 4) asm volatile("s_waitcnt vmcnt(8)" ::: "memory");
            else                   asm volatile("s_waitcnt vmcnt(6)" ::: "memory");
        } else if (kt == nk - 2) {
            if constexpr (NI == 4) asm volatile("s_waitcnt vmcnt(4)" ::: "memory");
            else                   asm volatile("s_waitcnt vmcnt(3)" ::: "memory");
        } else {
            asm volatile("s_waitcnt vmcnt(0)" ::: "memory");
        }
        asm volatile("s_waitcnt lgkmcnt(0)" ::: "memory");  // slot reads of kt-1 done
        asm volatile("s_barrier" ::: "memory");             // no compiler drain added
        if (kt + 3 < nk) stage(kt + 3);                     // into slot (kt-1)&3: safe

        s16x8 af[8], bf[NI];
#pragma unroll
        for (int mi = 0; mi < 8; ++mi)
            af[mi] = *reinterpret_cast<const s16x8*>(
                &sm[s][0][(wm * 128 + mi * 16 + lo) * 32 + ((hi ^ (lo & 3)) * 8)]);
#pragma unroll
        for (int ni = 0; ni < NI; ++ni)
            bf[ni] = *reinterpret_cast<const s16x8*>(
                &sm[s][1][(wn * NI * 16 + ni * 16 + lo) * 32 + ((hi ^ (lo & 3)) * 8)]);
        __builtin_amdgcn_s_setprio(1);
#pragma unroll
        for (int mi = 0; mi < 8; ++mi)
#pragma unroll
            for (int ni = 0; ni < NI; ++ni)
                acc[mi][ni] = __builtin_amdgcn_mfma_f32_16x16x32_bf16(af[mi], bf[ni], acc[mi][ni], 0, 0, 0);
        __builtin_amdgcn_s_setprio(0);
    }
    const int rbase = row0 + wm * 128 + hi * 4;
    const int cbase = col0 + wn * NI * 16 + lo;
#pragma unroll
    for (int mi = 0; mi < 8; ++mi)
#pragma unroll
        for (int ni = 0; ni < NI; ++ni)
#pragma unroll
            for (int r = 0; r < 4; ++r)
                C[(size_t)(rbase + mi * 16 + r) * N + cbase + ni * 16] = acc[mi][ni][r];
}

// ---------------- RoPE + scatter (Q/K only, float4-vectorized) ----------------
__global__ __launch_bounds__(256)
void rope_scatter(const float* __restrict__ qkv,
                  const float* __restrict__ cosT, const float* __restrict__ sinT,
                  __hip_bfloat16* __restrict__ Qr, __hip_bfloat16* __restrict__ Kr) {
    const int m = blockIdx.y;                           // token row, 0..4095
    const int col4 = blockIdx.x * 256 + threadIdx.x;    // 0..639
    if (col4 >= 640) return;
    const int col = col4 * 4;
    const int b = m >> 11, s = m & 2047;
    const int d = col & 127;                            // 4-aligned
    const int j = d & 63;
    const f32x4 v = *reinterpret_cast<const f32x4*>(qkv + (size_t)m * 3072 + col);
    const f32x4 p = *reinterpret_cast<const f32x4*>(qkv + (size_t)m * 3072 + (col ^ 64));
    const f32x4 c4 = *reinterpret_cast<const f32x4*>(cosT + s * 64 + j);
    const f32x4 s4 = *reinterpret_cast<const f32x4*>(sinT + s * 64 + j);
    const float sgn = (d < 64) ? -1.f : 1.f;
    union { s16x4 v4; __hip_bfloat16 h[4]; } u;
#pragma unroll
    for (int i = 0; i < 4; ++i)
        u.h[i] = __float2bfloat16(v[i] * c4[i] + sgn * p[i] * s4[i]);
    if (col < 2048) {
        const int hh = col >> 7;
        *reinterpret_cast<s16x4*>(&Qr[((size_t)(b * 16 + hh) * 2048 + s) * 128 + d]) = u.v4;
    } else {
        const int hh = (col - 2048) >> 7;
        *reinterpret_cast<s16x4*>(&Kr[((size_t)(b * 4 + hh) * 2048 + s) * 128 + d]) = u.v4;
    }
}

// ---------------- flash attention: 128 Q-rows/block (8 waves), KV tiles of 64 ----------------
// Swapped QK^T (T12) + in-register exp2-domain softmax + defer-max (T13) +
// double-buffered K/V with ONE barrier per tile; x2 unroll for static LDS bases.
// __launch_bounds__ 2nd arg = min waves per EU: (512,4) -> 4*4/8 = 2 blocks/CU,
// matching the 80KB-LDS cap. ((512,2) declared 1 block/CU and halved occupancy.)
// Mask bias loads issued BEFORE the K/V prefetch so the post-QK fmaf waits
// vmcnt(8), not vmcnt(0) -> prefetch stays in flight across the tile (T14).
__global__ __launch_bounds__(512, 4)
void attn_kernel(const __hip_bfloat16* __restrict__ Qr,
                 const __hip_bfloat16* __restrict__ Kr,
                 const __hip_bfloat16* __restrict__ Vt,
                 const float* __restrict__ maskb,
                 __hip_bfloat16* __restrict__ Oo) {
    const int S = 2048;
    const int qt = blockIdx.x;                          // 0..15 (128 q-rows per block)
    const int bh = blockIdx.y;                          // 0..31
    const int b = bh >> 4, h = bh & 15, kvh = h >> 2;
    const int tid = threadIdx.x;
    const int l = tid & 63, w = tid >> 6;               // 8 waves
    const int lo = l & 15, hi = l >> 4;
    __shared__ __align__(16) __hip_bfloat16 Ks[2][64 * 128];   // [kv][d], swizzled
    __shared__ __align__(16) __hip_bfloat16 Vs[2][128 * 64];   // [d][kv], swizzled
    __shared__ __align__(16) __hip_bfloat16 Ps[8][16 * 64];    // per-wave [q][kv], swizzled

    const __hip_bfloat16* Qb = Qr + (size_t)(b * 16 + h) * S * 128;
    const __hip_bfloat16* Kb = Kr + (size_t)(b * 4 + kvh) * S * 128;
    const __hip_bfloat16* Vb = Vt + (size_t)(b * 4 + kvh) * 128 * S;
    const float* mrow = maskb + b * S;

    // Q fragments in registers: wave owns rows qt*128 + w*16 .. +15
    const int qrow = qt * 128 + w * 16 + lo;
    s16x8 qf[4];
#pragma unroll
    for (int kc = 0; kc < 4; ++kc)
        qf[kc] = *reinterpret_cast<const s16x8*>(Qb + (size_t)qrow * 128 + kc * 32 + hi * 8);

    float m_run = -1e30f, l_run = 0.f;                  // exp2-domain; lane's q-row = lo
    f32x4 o[8];
#pragma unroll
    for (int n = 0; n < 8; ++n) o[n] = f32x4{0.f, 0.f, 0.f, 0.f};
    const float scale2 = 0.12751682f;                   // 1/sqrt(128) * log2(e)

    // --- staging geometry ---
    const int krow = tid >> 4, kc8 = tid & 15;          // krow 0..31 (+i*32)
    const int koff = (kc8 ^ (krow & 7)) * 8;
    const int vrow = tid >> 3, vc8 = tid & 7;           // vrow 0..63 (+i*64)
    const int voff = (vc8 ^ (vrow & 7)) * 8;

    s16x8 kreg[2], vreg[2];
    auto load_tile = [&](int kv0) {
#pragma unroll
        for (int i = 0; i < 2; ++i)
            kreg[i] = *reinterpret_cast<const s16x8*>(
                Kb + (size_t)(kv0 + i * 32 + krow) * 128 + kc8 * 8);
#pragma unroll
        for (int i = 0; i < 2; ++i)
            vreg[i] = *reinterpret_cast<const s16x8*>(
                Vb + (size_t)(i * 64 + vrow) * S + kv0 + vc8 * 8);
    };

    auto body = [&](int kt, __hip_bfloat16* Kc, __hip_bfloat16* Vc) {
        const int kv0 = kt * 64;
        // mask bias FIRST (so later use waits vmcnt(8), keeping prefetch in flight)
        f32x4 bi[4];
#pragma unroll
        for (int ksub = 0; ksub < 4; ++ksub)
            bi[ksub] = *reinterpret_cast<const f32x4*>(mrow + kv0 + ksub * 16 + hi * 4);
#pragma unroll
        for (int i = 0; i < 2; ++i)
            *reinterpret_cast<s16x8*>(Kc + (i * 32 + krow) * 128 + koff) = kreg[i];
#pragma unroll
        for (int i = 0; i < 2; ++i)
            *reinterpret_cast<s16x8*>(Vc + (i * 64 + vrow) * 64 + voff) = vreg[i];
        if (kt < 31) load_tile(kv0 + 64);               // lands under compute (T14)
        __syncthreads();                                // buf ready for all

        // P^T = (K Q^T): lane holds P[kv=ksub*16+hi*4+r][q=lo]
        f32x4 sc[4] = {};
        __builtin_amdgcn_s_setprio(1);
#pragma unroll
        for (int ksub = 0; ksub < 4; ++ksub) {
            const int kr = ksub * 16 + lo;
            const int ksw = kr & 7;
#pragma unroll
            for (int kc = 0; kc < 4; ++kc) {
                s16x8 kf = *reinterpret_cast<const s16x8*>(
                    Kc + kr * 128 + (((kc * 4 + hi) ^ ksw) * 8));
                sc[ksub] = __builtin_amdgcn_mfma_f32_16x16x32_bf16(kf, qf[kc], sc[ksub], 0, 0, 0);
            }
        }
        __builtin_amdgcn_s_setprio(0);
        // scale (log2-domain) + additive mask bias
#pragma unroll
        for (int ksub = 0; ksub < 4; ++ksub)
#pragma unroll
            for (int r = 0; r < 4; ++r)
                sc[ksub][r] = fmaf(sc[ksub][r], scale2, bi[ksub][r]);
        // tile row-max
        float a0 = fmaxf(fmaxf(sc[0][0], sc[0][1]), fmaxf(sc[0][2], sc[0][3]));
        float a1 = fmaxf(fmaxf(sc[1][0], sc[1][1]), fmaxf(sc[1][2], sc[1][3]));
        float a2 = fmaxf(fmaxf(sc[2][0], sc[2][1]), fmaxf(sc[2][2], sc[2][3]));
        float a3 = fmaxf(fmaxf(sc[3][0], sc[3][1]), fmaxf(sc[3][2], sc[3][3]));
        float mx = fmaxf(fmaxf(a0, a1), fmaxf(a2, a3));
        mx = fmaxf(mx, __shfl_xor(mx, 16));
        mx = fmaxf(mx, __shfl_xor(mx, 32));
        // defer-max: only rescale when some row's max grew past 8*log2e
        if (__ballot(mx > m_run + 11.5417f) != 0ull) {
            const float mnew = fmaxf(m_run, mx);
            const float alpha = fexp2(m_run - mnew);
            m_run = mnew;
            l_run *= alpha;
            float ar[4];
#pragma unroll
            for (int r = 0; r < 4; ++r) ar[r] = __shfl(alpha, hi * 4 + r);
#pragma unroll
            for (int n = 0; n < 8; ++n)
#pragma unroll
                for (int r = 0; r < 4; ++r) o[n][r] *= ar[r];
        }
        // exp2 + row-sum (P bounded by 2^11.54 = e^8 under defer)
        float s0 = 0.f, s1 = 0.f, s2 = 0.f, s3 = 0.f;
#pragma unroll
        for (int r = 0; r < 4; ++r) {
            sc[0][r] = fexp2(sc[0][r] - m_run); s0 += sc[0][r];
            sc[1][r] = fexp2(sc[1][r] - m_run); s1 += sc[1][r];
            sc[2][r] = fexp2(sc[2][r] - m_run); s2 += sc[2][r];
            sc[3][r] = fexp2(sc[3][r] - m_run); s3 += sc[3][r];
        }
        float ssum = (s0 + s1) + (s2 + s3);
        ssum += __shfl_xor(ssum, 16);
        ssum += __shfl_xor(ssum, 32);
        l_run += ssum;
        // P -> LDS: cvt_pk pairs, one b64 per ksub (row q=lo, cols ksub*16+hi*4..+3)
        __hip_bfloat16* pb = &Ps[w][0];
#pragma unroll
        for (int ksub = 0; ksub < 4; ++ksub) {
            unsigned int d0, d1;
            asm("v_cvt_pk_bf16_f32 %0, %1, %2" : "=v"(d0) : "v"(sc[ksub][0]), "v"(sc[ksub][1]));
            asm("v_cvt_pk_bf16_f32 %0, %1, %2" : "=v"(d1) : "v"(sc[ksub][2]), "v"(sc[ksub][3]));
            const int byteoff = lo * 128 + (((ksub * 2 + (hi >> 1)) ^ (lo & 7)) * 16) + (hi & 1) * 8;
            uint2 dd; dd.x = d0; dd.y = d1;
            *reinterpret_cast<uint2*>(reinterpret_cast<char*>(pb) + byteoff) = dd;
        }
        // O += P V
        __builtin_amdgcn_s_setprio(1);
#pragma unroll
        for (int kg = 0; kg < 2; ++kg) {
            s16x8 pa = *reinterpret_cast<const s16x8*>(
                pb + lo * 64 + (((kg * 4 + hi) ^ (lo & 7)) * 8));
#pragma unroll
            for (int n = 0; n < 8; ++n) {
                const int vr = n * 16 + lo;
                s16x8 vb = *reinterpret_cast<const s16x8*>(
                    Vc + vr * 64 + (((kg * 4 + hi) ^ (vr & 7)) * 8));
                o[n] = __builtin_amdgcn_mfma_f32_16x16x32_bf16(pa, vb, o[n], 0, 0, 0);
            }
        }
        __builtin_amdgcn_s_setprio(0);
        // no trailing barrier: next call writes the other buffer
    };

    load_tile(0);
    for (int kt2 = 0; kt2 < 16; ++kt2) {                // x2 unroll: static LDS bases
        body(2 * kt2,     &Ks[0][0], &Vs[0][0]);
        body(2 * kt2 + 1, &Ks[1][0], &Vs[1][0]);
    }
    // epilogue: attn_out[b*S+s][h*128+d] = o / l   (l lives at lane q)
    float lr[4];
#pragma unroll
    for (int r = 0; r < 4; ++r) lr[r] = __shfl(l_run, hi * 4 + r);
    const int orow = b * S + qt * 128 + w * 16 + (hi * 4);
    const int ocol = h * 128 + lo;
#pragma unroll
    for (int n = 0; n < 8; ++n)
#pragma unroll
        for (int r = 0; r < 4; ++r)
            Oo[(size_t)(orow + r) * 2048 + ocol + n * 16] = __float2bfloat16(o[n][r] / lr[r]);
}

// ---------------- host launch ----------------
extern "C" void kernel_launch(void* const* d_in, const int* in_sizes, int n_in,
                              void* d_out, int out_size, void* d_ws, size_t ws_size,
                              hipStream_t stream) {
    const float* x  = (const float*)d_in[0];
    const int* mask = (const int*)d_in[1];
    const float* Wq = (const float*)d_in[2];
    const float* Wk = (const float*)d_in[3];
    const float* Wv = (const float*)d_in[4];
    const float* Wo = (const float*)d_in[5];
    float* out = (float*)d_out;

    char* ws = (char*)d_ws;
    size_t off = 0;
    auto alloc = [&](size_t bytes) -> void* {
        void* p = ws + off;
        off += (bytes + 255) & ~(size_t)255;
        return p;
    };
    __hip_bfloat16* xb     = (__hip_bfloat16*)alloc(4096ULL * 2048 * 2);   // 16 MB
    __hip_bfloat16* wqkv_t = (__hip_bfloat16*)alloc(3072ULL * 2048 * 2);   // 12 MB
    __hip_bfloat16* wo_t   = (__hip_bfloat16*)alloc(2048ULL * 2048 * 2);   // 8 MB
    float*          qkv    = (float*)alloc(4096ULL * 3072 * 4);            // 48 MB
    __hip_bfloat16* Kr     = (__hip_bfloat16*)alloc(2ULL * 4 * 2048 * 128 * 2);  // 4 MB
    __hip_bfloat16* Vt     = (__hip_bfloat16*)alloc(2ULL * 4 * 2048 * 128 * 2);  // 4 MB
    float*          cosT   = (float*)alloc(2048ULL * 64 * 4);
    float*          sinT   = (float*)alloc(2048ULL * 64 * 4);
    float*          maskb  = (float*)alloc(2ULL * 2048 * 4);
    // Aliases (regions dead by the time these are written):
    __hip_bfloat16* Qr    = xb;                   // xb dead after QKV GEMM; Qr written after
    __hip_bfloat16* attno = (__hip_bfloat16*)qkv; // qkv dead after rope/vt; attno written after

    rope_tables<<<dim3(2048), dim3(64), 0, stream>>>(cosT, sinT);
    mask_bias<<<dim3(16), dim3(256), 0, stream>>>(mask, maskb, 4096);
    cast_f32_bf16<<<dim3(8192), dim3(256), 0, stream>>>(x, xb, 2097152);
    transpose_cast<<<dim3(64, 64), dim3(32, 8), 0, stream>>>(Wq, wqkv_t, 2048, 2048);
    transpose_cast<<<dim3(16, 64), dim3(32, 8), 0, stream>>>(Wk, wqkv_t + 2048ULL * 2048, 2048, 512);
    transpose_cast<<<dim3(16, 64), dim3(32, 8), 0, stream>>>(Wv, wqkv_t + 2560ULL * 2048, 2048, 512);
    transpose_cast<<<dim3(64, 64), dim3(32, 8), 0, stream>>>(Wo, wo_t, 2048, 2048);

    // QKV: 256x256 tiles -> grid (12,16)
    gemm256_bt_f32<4><<<dim3(12, 16), dim3(512), 0, stream>>>(xb, wqkv_t, qkv, 4096, 3072, 2048);
    rope_scatter<<<dim3(3, 4096), dim3(256), 0, stream>>>(qkv, cosT, sinT, Qr, Kr);
    vt_transpose<<<dim3(64, 4, 8), dim3(32, 8), 0, stream>>>(qkv, Vt);
    attn_kernel<<<dim3(16, 32), dim3(512), 0, stream>>>(Qr, Kr, Vt, maskb, attno);
    // Wo: 256x128 tiles -> grid (16,16) = 256 blocks (full chip)
    gemm256_bt_f32<2><<<dim3(16, 16), dim3(512), 0, stream>>>(attno, wo_t, out, 4096, 2048, 2048);
}

// Round 11
// 238.500 us; speedup vs baseline: 1.1110x; 1.0525x over previous
//
#include <hip/hip_runtime.h>
#include <hip/hip_bf16.h>

typedef __attribute__((ext_vector_type(4))) float f32x4;
typedef __attribute__((ext_vector_type(8))) short s16x8;
typedef __attribute__((ext_vector_type(4))) short s16x4;

__device__ __forceinline__ float fexp2(float x) {   // 2^x (hw interlocked on CDNA)
    float y; asm("v_exp_f32 %0, %1" : "=v"(y) : "v"(x)); return y;
}

// ---------------- RoPE tables (tiny, double precision) ----------------
__global__ void rope_tables(float* __restrict__ cosT, float* __restrict__ sinT) {
    const int s = blockIdx.x, j = threadIdx.x;          // s in [0,2048), j in [0,64)
    const double inv = pow(10000.0, -(double)j / 64.0);
    const double f = (double)s * inv;
    cosT[s * 64 + j] = (float)cos(f);
    sinT[s * 64 + j] = (float)sin(f);
}

// ---------------- mask -> additive float bias ----------------
__global__ void mask_bias(const int* __restrict__ mask, float* __restrict__ mb, int n) {
    const int i = blockIdx.x * 256 + threadIdx.x;
    if (i < n) mb[i] = (mask[i] == 0) ? -1e30f : 0.f;
}

// ---------------- cast fp32 -> bf16 (vectorized) ----------------
__global__ __launch_bounds__(256)
void cast_f32_bf16(const float* __restrict__ src, __hip_bfloat16* __restrict__ dst, int n4) {
    const int i = blockIdx.x * 256 + threadIdx.x;
    if (i < n4) {
        f32x4 v = *reinterpret_cast<const f32x4*>(src + (size_t)i * 4);
        union { s16x4 v4; __hip_bfloat16 h[4]; } u;
#pragma unroll
        for (int j = 0; j < 4; ++j) u.h[j] = __float2bfloat16(v[j]);
        *reinterpret_cast<s16x4*>(dst + (size_t)i * 4) = u.v4;
    }
}

// ---------------- tiled transpose + cast: dst[c][r] = (bf16)src[r][c] ----------------
__global__ __launch_bounds__(256)
void transpose_cast(const float* __restrict__ src, __hip_bfloat16* __restrict__ dst,
                    int R, int C) {
    __shared__ __align__(16) float t[32][33];
    const int tx = threadIdx.x, ty = threadIdx.y;       // (32, 8)
    const int r0 = blockIdx.y * 32, c0 = blockIdx.x * 32;
#pragma unroll
    for (int i = 0; i < 32; i += 8)
        t[ty + i][tx] = src[(size_t)(r0 + ty + i) * C + c0 + tx];
    __syncthreads();
#pragma unroll
    for (int i = 0; i < 32; i += 8)
        dst[(size_t)(c0 + ty + i) * R + r0 + tx] = __float2bfloat16(t[tx][ty + i]);
}

// ---------------- V slice of bf16 qkv -> Vt[b][hh][d][s] (bit-copy transpose) ----------------
__global__ __launch_bounds__(256)
void vt_transpose(const __hip_bfloat16* __restrict__ qkv, __hip_bfloat16* __restrict__ Vt) {
    __shared__ unsigned short t[32][33];
    const int tx = threadIdx.x, ty = threadIdx.y;       // (32, 8)
    const int s0 = blockIdx.x * 32, d0 = blockIdx.y * 32;
    const int bh = blockIdx.z, b = bh >> 2, hh = bh & 3;
    const unsigned short* q = (const unsigned short*)qkv;
#pragma unroll
    for (int i = 0; i < 32; i += 8)
        t[ty + i][tx] = q[(size_t)(b * 2048 + s0 + ty + i) * 3072 + 2560 + hh * 128 + d0 + tx];
    __syncthreads();
#pragma unroll
    for (int i = 0; i < 32; i += 8)
        ((unsigned short*)Vt)[((size_t)(bh * 128) + d0 + ty + i) * 2048 + s0 + tx] = t[tx][ty + i];
}

// ---------------- 256-row-tile GEMM, counted-vmcnt 4-slot pipeline (T4) ----------
// LDS swizzle f(r)=(r>>1)&3: slot s of row r holds logical chunk s^f(r).
// Bank arithmetic: 64B rows -> bank = 16*(r&1) + 4*slot; (r&1, slot) spans 8
// distinct pairs over 16 lanes -> 2-way (free).  (old ^(r&3) was 4-way.)
// XCD swizzle (T1): 1-D grid, id&7 = XCD; each XCD owns 2 grid rows (NY=16,
// grid%8==0 -> bijective) so an A-panel lives in ONE per-XCD L2.
template<int NI, bool BF16OUT>   // NI: 4 -> BN=256, 2 -> BN=128
__global__ __launch_bounds__(512, 1)
void gemm256_bt(const __hip_bfloat16* __restrict__ A,
                const __hip_bfloat16* __restrict__ Bt,
                void* __restrict__ Cv, int M, int N, int K, int NX) {
    constexpr int NB = NI / 2;                          // B-stage loads per thread
    __shared__ __align__(16) __hip_bfloat16 sm[4][2][8192];
    const int tid = threadIdx.x;
    const int l = tid & 63, w = tid >> 6;               // 8 waves
    const int lo = l & 15, hi = l >> 4;
    const int wm = w >> 2, wn = w & 3;
    // XCD-chunked decode: xcd = id&7 owns rows {2*xcd, 2*xcd+1}
    const int id = blockIdx.x, slot = id >> 3;
    const int by = (id & 7) * 2 + slot / NX;
    const int bx = slot % NX;
    const int row0 = by * 256;
    const int col0 = bx * (NI * 64);
    const int nk = K >> 5;

    f32x4 acc[8][NI];
#pragma unroll
    for (int mi = 0; mi < 8; ++mi)
#pragma unroll
        for (int ni = 0; ni < NI; ++ni) acc[mi][ni] = f32x4{0.f, 0.f, 0.f, 0.f};

    auto stage = [&](int kt) {
        const int s = kt & 3, k0 = kt << 5;
#pragma unroll
        for (int i = 0; i < 2; ++i) {                   // A: 256 rows x 4 chunks
            const int c = i * 512 + tid;
            const int r = c >> 2, sw = ((c & 3) ^ ((r >> 1) & 3)) * 8;
            __builtin_amdgcn_global_load_lds(
                (const __attribute__((address_space(1))) void*)(A + (size_t)(row0 + r) * K + k0 + sw),
                (__attribute__((address_space(3))) void*)(&sm[s][0][c * 8]), 16, 0, 0);
        }
#pragma unroll
        for (int i = 0; i < NB; ++i) {                  // B: NI*64 rows x 4 chunks
            const int c = i * 512 + tid;
            const int r = c >> 2, sw = ((c & 3) ^ ((r >> 1) & 3)) * 8;
            __builtin_amdgcn_global_load_lds(
                (const __attribute__((address_space(1))) void*)(Bt + (size_t)(col0 + r) * K + k0 + sw),
                (__attribute__((address_space(3))) void*)(&sm[s][1][c * 8]), 16, 0, 0);
        }
    };

    stage(0); stage(1); stage(2);                       // 3 tiles ahead
    for (int kt = 0; kt < nk; ++kt) {
        const int s = kt & 3;
        if (kt < nk - 2) {
            if constexpr (NI == 4) asm volatile("s_waitcnt vmcnt(8)" ::: "memory");
            else                   asm volatile("s_waitcnt vmcnt(6)" ::: "memory");
        } else if (kt == nk - 2) {
            if constexpr (NI == 4) asm volatile("s_waitcnt vmcnt(4)" ::: "memory");
            else                   asm volatile("s_waitcnt vmcnt(3)" ::: "memory");
        } else {
            asm volatile("s_waitcnt vmcnt(0)" ::: "memory");
        }
        asm volatile("s_waitcnt lgkmcnt(0)" ::: "memory");  // slot reads of kt-1 done
        asm volatile("s_barrier" ::: "memory");             // no compiler drain added
        if (kt + 3 < nk) stage(kt + 3);                     // into slot (kt-1)&3: safe

        s16x8 af[8], bf[NI];
        const int rsw = ((lo >> 1) & 3);                // f(row), row base %16 == 0
#pragma unroll
        for (int mi = 0; mi < 8; ++mi)
            af[mi] = *reinterpret_cast<const s16x8*>(
                &sm[s][0][(wm * 128 + mi * 16 + lo) * 32 + ((hi ^ rsw) * 8)]);
#pragma unroll
        for (int ni = 0; ni < NI; ++ni)
            bf[ni] = *reinterpret_cast<const s16x8*>(
                &sm[s][1][(wn * NI * 16 + ni * 16 + lo) * 32 + ((hi ^ rsw) * 8)]);
        __builtin_amdgcn_s_setprio(1);
#pragma unroll
        for (int mi = 0; mi < 8; ++mi)
#pragma unroll
            for (int ni = 0; ni < NI; ++ni)
                acc[mi][ni] = __builtin_amdgcn_mfma_f32_16x16x32_bf16(af[mi], bf[ni], acc[mi][ni], 0, 0, 0);
        __builtin_amdgcn_s_setprio(0);
    }
    const int rbase = row0 + wm * 128 + hi * 4;
    const int cbase = col0 + wn * NI * 16 + lo;
    if constexpr (BF16OUT) {
        __hip_bfloat16* C = (__hip_bfloat16*)Cv;
#pragma unroll
        for (int mi = 0; mi < 8; ++mi)
#pragma unroll
            for (int ni = 0; ni < NI; ++ni)
#pragma unroll
                for (int r = 0; r < 4; ++r)
                    C[(size_t)(rbase + mi * 16 + r) * N + cbase + ni * 16] =
                        __float2bfloat16(acc[mi][ni][r]);
    } else {
        float* C = (float*)Cv;
#pragma unroll
        for (int mi = 0; mi < 8; ++mi)
#pragma unroll
            for (int ni = 0; ni < NI; ++ni)
#pragma unroll
                for (int r = 0; r < 4; ++r)
                    C[(size_t)(rbase + mi * 16 + r) * N + cbase + ni * 16] = acc[mi][ni][r];
    }
}

// ---------------- RoPE + scatter (Q/K only, bf16 in/out, vectorized) ----------------
__global__ __launch_bounds__(256)
void rope_scatter(const __hip_bfloat16* __restrict__ qkv,
                  const float* __restrict__ cosT, const float* __restrict__ sinT,
                  __hip_bfloat16* __restrict__ Qr, __hip_bfloat16* __restrict__ Kr) {
    const int m = blockIdx.y;                           // token row, 0..4095
    const int col4 = blockIdx.x * 256 + threadIdx.x;    // 0..639
    if (col4 >= 640) return;
    const int col = col4 * 4;
    const int b = m >> 11, s = m & 2047;
    const int d = col & 127;                            // 4-aligned
    const int j = d & 63;
    union { s16x4 v4; __hip_bfloat16 h[4]; } vv, pp, u;
    vv.v4 = *reinterpret_cast<const s16x4*>(qkv + (size_t)m * 3072 + col);
    pp.v4 = *reinterpret_cast<const s16x4*>(qkv + (size_t)m * 3072 + (col ^ 64));
    const f32x4 c4 = *reinterpret_cast<const f32x4*>(cosT + s * 64 + j);
    const f32x4 s4 = *reinterpret_cast<const f32x4*>(sinT + s * 64 + j);
    const float sgn = (d < 64) ? -1.f : 1.f;
#pragma unroll
    for (int i = 0; i < 4; ++i)
        u.h[i] = __float2bfloat16(__bfloat162float(vv.h[i]) * c4[i] +
                                  sgn * __bfloat162float(pp.h[i]) * s4[i]);
    if (col < 2048) {
        const int hh = col >> 7;
        *reinterpret_cast<s16x4*>(&Qr[((size_t)(b * 16 + hh) * 2048 + s) * 128 + d]) = u.v4;
    } else {
        const int hh = (col - 2048) >> 7;
        *reinterpret_cast<s16x4*>(&Kr[((size_t)(b * 4 + hh) * 2048 + s) * 128 + d]) = u.v4;
    }
}

// ---------------- flash attention: 128 Q-rows/block (8 waves), KV tiles of 64 ----------------
// Swapped QK^T (T12) + in-register exp2-domain softmax + defer-max (T13) +
// double-buffered K/V with ONE barrier per tile; x2 unroll for static LDS bases.
// (512,4): 4 waves/EU * 4 EU / 8 waves = 2 blocks/CU, matching the 80KB LDS cap.
__global__ __launch_bounds__(512, 4)
void attn_kernel(const __hip_bfloat16* __restrict__ Qr,
                 const __hip_bfloat16* __restrict__ Kr,
                 const __hip_bfloat16* __restrict__ Vt,
                 const float* __restrict__ maskb,
                 __hip_bfloat16* __restrict__ Oo) {
    const int S = 2048;
    const int qt = blockIdx.x;                          // 0..15 (128 q-rows per block)
    const int bh = blockIdx.y;                          // 0..31
    const int b = bh >> 4, h = bh & 15, kvh = h >> 2;
    const int tid = threadIdx.x;
    const int l = tid & 63, w = tid >> 6;               // 8 waves
    const int lo = l & 15, hi = l >> 4;
    __shared__ __align__(16) __hip_bfloat16 Ks[2][64 * 128];   // [kv][d], swizzled
    __shared__ __align__(16) __hip_bfloat16 Vs[2][128 * 64];   // [d][kv], swizzled
    __shared__ __align__(16) __hip_bfloat16 Ps[8][16 * 64];    // per-wave [q][kv], swizzled

    const __hip_bfloat16* Qb = Qr + (size_t)(b * 16 + h) * S * 128;
    const __hip_bfloat16* Kb = Kr + (size_t)(b * 4 + kvh) * S * 128;
    const __hip_bfloat16* Vb = Vt + (size_t)(b * 4 + kvh) * 128 * S;
    const float* mrow = maskb + b * S;

    // Q fragments in registers: wave owns rows qt*128 + w*16 .. +15
    const int qrow = qt * 128 + w * 16 + lo;
    s16x8 qf[4];
#pragma unroll
    for (int kc = 0; kc < 4; ++kc)
        qf[kc] = *reinterpret_cast<const s16x8*>(Qb + (size_t)qrow * 128 + kc * 32 + hi * 8);

    float m_run = -1e30f, l_run = 0.f;                  // exp2-domain; lane's q-row = lo
    f32x4 o[8];
#pragma unroll
    for (int n = 0; n < 8; ++n) o[n] = f32x4{0.f, 0.f, 0.f, 0.f};
    const float scale2 = 0.12751682f;                   // 1/sqrt(128) * log2(e)

    // --- staging geometry ---
    const int krow = tid >> 4, kc8 = tid & 15;          // krow 0..31 (+i*32)
    const int koff = (kc8 ^ (krow & 7)) * 8;
    const int vrow = tid >> 3, vc8 = tid & 7;           // vrow 0..63 (+i*64)
    const int voff = (vc8 ^ (vrow & 7)) * 8;

    s16x8 kreg[2], vreg[2];
    auto load_tile = [&](int kv0) {
#pragma unroll
        for (int i = 0; i < 2; ++i)
            kreg[i] = *reinterpret_cast<const s16x8*>(
                Kb + (size_t)(kv0 + i * 32 + krow) * 128 + kc8 * 8);
#pragma unroll
        for (int i = 0; i < 2; ++i)
            vreg[i] = *reinterpret_cast<const s16x8*>(
                Vb + (size_t)(i * 64 + vrow) * S + kv0 + vc8 * 8);
    };

    auto body = [&](int kt, __hip_bfloat16* Kc, __hip_bfloat16* Vc) {
        const int kv0 = kt * 64;
        // mask bias FIRST (so later use waits vmcnt(8), keeping prefetch in flight)
        f32x4 bi[4];
#pragma unroll
        for (int ksub = 0; ksub < 4; ++ksub)
            bi[ksub] = *reinterpret_cast<const f32x4*>(mrow + kv0 + ksub * 16 + hi * 4);
#pragma unroll
        for (int i = 0; i < 2; ++i)
            *reinterpret_cast<s16x8*>(Kc + (i * 32 + krow) * 128 + koff) = kreg[i];
#pragma unroll
        for (int i = 0; i < 2; ++i)
            *reinterpret_cast<s16x8*>(Vc + (i * 64 + vrow) * 64 + voff) = vreg[i];
        if (kt < 31) load_tile(kv0 + 64);               // lands under compute (T14)
        __syncthreads();                                // buf ready for all

        // P^T = (K Q^T): lane holds P[kv=ksub*16+hi*4+r][q=lo]
        f32x4 sc[4] = {};
        __builtin_amdgcn_s_setprio(1);
#pragma unroll
        for (int ksub = 0; ksub < 4; ++ksub) {
            const int kr = ksub * 16 + lo;
            const int ksw = kr & 7;
#pragma unroll
            for (int kc = 0; kc < 4; ++kc) {
                s16x8 kf = *reinterpret_cast<const s16x8*>(
                    Kc + kr * 128 + (((kc * 4 + hi) ^ ksw) * 8));
                sc[ksub] = __builtin_amdgcn_mfma_f32_16x16x32_bf16(kf, qf[kc], sc[ksub], 0, 0, 0);
            }
        }
        __builtin_amdgcn_s_setprio(0);
        // scale (log2-domain) + additive mask bias
#pragma unroll
        for (int ksub = 0; ksub < 4; ++ksub)
#pragma unroll
            for (int r = 0; r < 4; ++r)
                sc[ksub][r] = fmaf(sc[ksub][r], scale2, bi[ksub][r]);
        // tile row-max
        float a0 = fmaxf(fmaxf(sc[0][0], sc[0][1]), fmaxf(sc[0][2], sc[0][3]));
        float a1 = fmaxf(fmaxf(sc[1][0], sc[1][1]), fmaxf(sc[1][2], sc[1][3]));
        float a2 = fmaxf(fmaxf(sc[2][0], sc[2][1]), fmaxf(sc[2][2], sc[2][3]));
        float a3 = fmaxf(fmaxf(sc[3][0], sc[3][1]), fmaxf(sc[3][2], sc[3][3]));
        float mx = fmaxf(fmaxf(a0, a1), fmaxf(a2, a3));
        mx = fmaxf(mx, __shfl_xor(mx, 16));
        mx = fmaxf(mx, __shfl_xor(mx, 32));
        // defer-max: only rescale when some row's max grew past 8*log2e
        if (__ballot(mx > m_run + 11.5417f) != 0ull) {
            const float mnew = fmaxf(m_run, mx);
            const float alpha = fexp2(m_run - mnew);
            m_run = mnew;
            l_run *= alpha;
            float ar[4];
#pragma unroll
            for (int r = 0; r < 4; ++r) ar[r] = __shfl(alpha, hi * 4 + r);
#pragma unroll
            for (int n = 0; n < 8; ++n)
#pragma unroll
                for (int r = 0; r < 4; ++r) o[n][r] *= ar[r];
        }
        // exp2 + row-sum (P bounded by 2^11.54 = e^8 under defer)
        float s0 = 0.f, s1 = 0.f, s2 = 0.f, s3 = 0.f;
#pragma unroll
        for (int r = 0; r < 4; ++r) {
            sc[0][r] = fexp2(sc[0][r] - m_run); s0 += sc[0][r];
            sc[1][r] = fexp2(sc[1][r] - m_run); s1 += sc[1][r];
            sc[2][r] = fexp2(sc[2][r] - m_run); s2 += sc[2][r];
            sc[3][r] = fexp2(sc[3][r] - m_run); s3 += sc[3][r];
        }
        float ssum = (s0 + s1) + (s2 + s3);
        ssum += __shfl_xor(ssum, 16);
        ssum += __shfl_xor(ssum, 32);
        l_run += ssum;
        // P -> LDS: cvt_pk pairs, one b64 per ksub (row q=lo, cols ksub*16+hi*4..+3)
        __hip_bfloat16* pb = &Ps[w][0];
#pragma unroll
        for (int ksub = 0; ksub < 4; ++ksub) {
            unsigned int d0, d1;
            asm("v_cvt_pk_bf16_f32 %0, %1, %2" : "=v"(d0) : "v"(sc[ksub][0]), "v"(sc[ksub][1]));
            asm("v_cvt_pk_bf16_f32 %0, %1, %2" : "=v"(d1) : "v"(sc[ksub][2]), "v"(sc[ksub][3]));
            const int byteoff = lo * 128 + (((ksub * 2 + (hi >> 1)) ^ (lo & 7)) * 16) + (hi & 1) * 8;
            uint2 dd; dd.x = d0; dd.y = d1;
            *reinterpret_cast<uint2*>(reinterpret_cast<char*>(pb) + byteoff) = dd;
        }
        // O += P V
        __builtin_amdgcn_s_setprio(1);
#pragma unroll
        for (int kg = 0; kg < 2; ++kg) {
            s16x8 pa = *reinterpret_cast<const s16x8*>(
                pb + lo * 64 + (((kg * 4 + hi) ^ (lo & 7)) * 8));
#pragma unroll
            for (int n = 0; n < 8; ++n) {
                const int vr = n * 16 + lo;
                s16x8 vb = *reinterpret_cast<const s16x8*>(
                    Vc + vr * 64 + (((kg * 4 + hi) ^ (vr & 7)) * 8));
                o[n] = __builtin_amdgcn_mfma_f32_16x16x32_bf16(pa, vb, o[n], 0, 0, 0);
            }
        }
        __builtin_amdgcn_s_setprio(0);
        // no trailing barrier: next call writes the other buffer
    };

    load_tile(0);
    for (int kt2 = 0; kt2 < 16; ++kt2) {                // x2 unroll: static LDS bases
        body(2 * kt2,     &Ks[0][0], &Vs[0][0]);
        body(2 * kt2 + 1, &Ks[1][0], &Vs[1][0]);
    }
    // epilogue: attn_out[b*S+s][h*128+d] = o / l   (l lives at lane q)
    float lr[4];
#pragma unroll
    for (int r = 0; r < 4; ++r) lr[r] = __shfl(l_run, hi * 4 + r);
    const int orow = b * S + qt * 128 + w * 16 + (hi * 4);
    const int ocol = h * 128 + lo;
#pragma unroll
    for (int n = 0; n < 8; ++n)
#pragma unroll
        for (int r = 0; r < 4; ++r)
            Oo[(size_t)(orow + r) * 2048 + ocol + n * 16] = __float2bfloat16(o[n][r] / lr[r]);
}

// ---------------- host launch ----------------
extern "C" void kernel_launch(void* const* d_in, const int* in_sizes, int n_in,
                              void* d_out, int out_size, void* d_ws, size_t ws_size,
                              hipStream_t stream) {
    const float* x  = (const float*)d_in[0];
    const int* mask = (const int*)d_in[1];
    const float* Wq = (const float*)d_in[2];
    const float* Wk = (const float*)d_in[3];
    const float* Wv = (const float*)d_in[4];
    const float* Wo = (const float*)d_in[5];
    float* out = (float*)d_out;

    char* ws = (char*)d_ws;
    size_t off = 0;
    auto alloc = [&](size_t bytes) -> void* {
        void* p = ws + off;
        off += (bytes + 255) & ~(size_t)255;
        return p;
    };
    __hip_bfloat16* xb     = (__hip_bfloat16*)alloc(4096ULL * 2048 * 2);   // 16 MB
    __hip_bfloat16* wqkv_t = (__hip_bfloat16*)alloc(3072ULL * 2048 * 2);   // 12 MB
    __hip_bfloat16* wo_t   = (__hip_bfloat16*)alloc(2048ULL * 2048 * 2);   // 8 MB
    __hip_bfloat16* qkvb   = (__hip_bfloat16*)alloc(4096ULL * 3072 * 2);   // 24 MB (bf16 now)
    __hip_bfloat16* Kr     = (__hip_bfloat16*)alloc(2ULL * 4 * 2048 * 128 * 2);  // 4 MB
    __hip_bfloat16* Vt     = (__hip_bfloat16*)alloc(2ULL * 4 * 2048 * 128 * 2);  // 4 MB
    float*          cosT   = (float*)alloc(2048ULL * 64 * 4);
    float*          sinT   = (float*)alloc(2048ULL * 64 * 4);
    float*          maskb  = (float*)alloc(2ULL * 2048 * 4);
    __hip_bfloat16* attno  = (__hip_bfloat16*)alloc(4096ULL * 2048 * 2);   // 16 MB
    // Alias (xb dead after QKV GEMM; Qr written after):
    __hip_bfloat16* Qr    = xb;

    rope_tables<<<dim3(2048), dim3(64), 0, stream>>>(cosT, sinT);
    mask_bias<<<dim3(16), dim3(256), 0, stream>>>(mask, maskb, 4096);
    cast_f32_bf16<<<dim3(8192), dim3(256), 0, stream>>>(x, xb, 2097152);
    transpose_cast<<<dim3(64, 64), dim3(32, 8), 0, stream>>>(Wq, wqkv_t, 2048, 2048);
    transpose_cast<<<dim3(16, 64), dim3(32, 8), 0, stream>>>(Wk, wqkv_t + 2048ULL * 2048, 2048, 512);
    transpose_cast<<<dim3(16, 64), dim3(32, 8), 0, stream>>>(Wv, wqkv_t + 2560ULL * 2048, 2048, 512);
    transpose_cast<<<dim3(64, 64), dim3(32, 8), 0, stream>>>(Wo, wo_t, 2048, 2048);

    // QKV: 256x256 tiles, 1-D grid 192 (NX=12, NY=16), bf16 output
    gemm256_bt<4, true><<<dim3(192), dim3(512), 0, stream>>>(xb, wqkv_t, qkvb, 4096, 3072, 2048, 12);
    rope_scatter<<<dim3(3, 4096), dim3(256), 0, stream>>>(qkvb, cosT, sinT, Qr, Kr);
    vt_transpose<<<dim3(64, 4, 8), dim3(32, 8), 0, stream>>>(qkvb, Vt);
    attn_kernel<<<dim3(16, 32), dim3(512), 0, stream>>>(Qr, Kr, Vt, maskb, attno);
    // Wo: 256x128 tiles, 1-D grid 256 (NX=16, NY=16), fp32 output
    gemm256_bt<2, false><<<dim3(256), dim3(512), 0, stream>>>(attno, wo_t, out, 4096, 2048, 2048, 16);
}

// Round 12
// 226.014 us; speedup vs baseline: 1.1724x; 1.0552x over previous
//
#include <hip/hip_runtime.h>
#include <hip/hip_bf16.h>

typedef __attribute__((ext_vector_type(4))) float f32x4;
typedef __attribute__((ext_vector_type(16))) float f32x16;
typedef __attribute__((ext_vector_type(8))) short s16x8;
typedef __attribute__((ext_vector_type(4))) short s16x4;
typedef __attribute__((ext_vector_type(2))) unsigned int u32x2;

__device__ __forceinline__ float fexp2(float x) {   // 2^x
    float y; asm("v_exp_f32 %0, %1" : "=v"(y) : "v"(x)); return y;
}

// ---------------- RoPE tables (tiny, double precision) ----------------
__global__ void rope_tables(float* __restrict__ cosT, float* __restrict__ sinT) {
    const int s = blockIdx.x, j = threadIdx.x;          // s in [0,2048), j in [0,64)
    const double inv = pow(10000.0, -(double)j / 64.0);
    const double f = (double)s * inv;
    cosT[s * 64 + j] = (float)cos(f);
    sinT[s * 64 + j] = (float)sin(f);
}

// ---------------- mask -> additive float bias ----------------
__global__ void mask_bias(const int* __restrict__ mask, float* __restrict__ mb, int n) {
    const int i = blockIdx.x * 256 + threadIdx.x;
    if (i < n) mb[i] = (mask[i] == 0) ? -1e30f : 0.f;
}

// ---------------- cast fp32 -> bf16 (vectorized) ----------------
__global__ __launch_bounds__(256)
void cast_f32_bf16(const float* __restrict__ src, __hip_bfloat16* __restrict__ dst, int n4) {
    const int i = blockIdx.x * 256 + threadIdx.x;
    if (i < n4) {
        f32x4 v = *reinterpret_cast<const f32x4*>(src + (size_t)i * 4);
        union { s16x4 v4; __hip_bfloat16 h[4]; } u;
#pragma unroll
        for (int j = 0; j < 4; ++j) u.h[j] = __float2bfloat16(v[j]);
        *reinterpret_cast<s16x4*>(dst + (size_t)i * 4) = u.v4;
    }
}

// ---------------- tiled transpose + cast: dst[c][r] = (bf16)src[r][c] ----------------
__global__ __launch_bounds__(256)
void transpose_cast(const float* __restrict__ src, __hip_bfloat16* __restrict__ dst,
                    int R, int C) {
    __shared__ __align__(16) float t[32][33];
    const int tx = threadIdx.x, ty = threadIdx.y;       // (32, 8)
    const int r0 = blockIdx.y * 32, c0 = blockIdx.x * 32;
#pragma unroll
    for (int i = 0; i < 32; i += 8)
        t[ty + i][tx] = src[(size_t)(r0 + ty + i) * C + c0 + tx];
    __syncthreads();
#pragma unroll
    for (int i = 0; i < 32; i += 8)
        dst[(size_t)(c0 + ty + i) * R + r0 + tx] = __float2bfloat16(t[tx][ty + i]);
}

// ---------------- V slice of bf16 qkv -> Vt[b][hh][d][s] (bit-copy transpose) ----------------
__global__ __launch_bounds__(256)
void vt_transpose(const __hip_bfloat16* __restrict__ qkv, __hip_bfloat16* __restrict__ Vt) {
    __shared__ unsigned short t[32][33];
    const int tx = threadIdx.x, ty = threadIdx.y;       // (32, 8)
    const int s0 = blockIdx.x * 32, d0 = blockIdx.y * 32;
    const int bh = blockIdx.z, b = bh >> 2, hh = bh & 3;
    const unsigned short* q = (const unsigned short*)qkv;
#pragma unroll
    for (int i = 0; i < 32; i += 8)
        t[ty + i][tx] = q[(size_t)(b * 2048 + s0 + ty + i) * 3072 + 2560 + hh * 128 + d0 + tx];
    __syncthreads();
#pragma unroll
    for (int i = 0; i < 32; i += 8)
        ((unsigned short*)Vt)[((size_t)(bh * 128) + d0 + ty + i) * 2048 + s0 + tx] = t[tx][ty + i];
}

// ---------------- 256-row-tile GEMM, counted-vmcnt 4-slot pipeline (T4) ----------
template<int NI, bool BF16OUT>   // NI: 4 -> BN=256, 2 -> BN=128
__global__ __launch_bounds__(512, 1)
void gemm256_bt(const __hip_bfloat16* __restrict__ A,
                const __hip_bfloat16* __restrict__ Bt,
                void* __restrict__ Cv, int M, int N, int K, int NX) {
    constexpr int NB = NI / 2;                          // B-stage loads per thread
    __shared__ __align__(16) __hip_bfloat16 sm[4][2][8192];
    const int tid = threadIdx.x;
    const int l = tid & 63, w = tid >> 6;               // 8 waves
    const int lo = l & 15, hi = l >> 4;
    const int wm = w >> 2, wn = w & 3;
    const int id = blockIdx.x, slot = id >> 3;
    const int by = (id & 7) * 2 + slot / NX;
    const int bx = slot % NX;
    const int row0 = by * 256;
    const int col0 = bx * (NI * 64);
    const int nk = K >> 5;

    f32x4 acc[8][NI];
#pragma unroll
    for (int mi = 0; mi < 8; ++mi)
#pragma unroll
        for (int ni = 0; ni < NI; ++ni) acc[mi][ni] = f32x4{0.f, 0.f, 0.f, 0.f};

    auto stage = [&](int kt) {
        const int s = kt & 3, k0 = kt << 5;
#pragma unroll
        for (int i = 0; i < 2; ++i) {                   // A: 256 rows x 4 chunks
            const int c = i * 512 + tid;
            const int r = c >> 2, sw = ((c & 3) ^ ((r >> 1) & 3)) * 8;
            __builtin_amdgcn_global_load_lds(
                (const __attribute__((address_space(1))) void*)(A + (size_t)(row0 + r) * K + k0 + sw),
                (__attribute__((address_space(3))) void*)(&sm[s][0][c * 8]), 16, 0, 0);
        }
#pragma unroll
        for (int i = 0; i < NB; ++i) {                  // B: NI*64 rows x 4 chunks
            const int c = i * 512 + tid;
            const int r = c >> 2, sw = ((c & 3) ^ ((r >> 1) & 3)) * 8;
            __builtin_amdgcn_global_load_lds(
                (const __attribute__((address_space(1))) void*)(Bt + (size_t)(col0 + r) * K + k0 + sw),
                (__attribute__((address_space(3))) void*)(&sm[s][1][c * 8]), 16, 0, 0);
        }
    };

    stage(0); stage(1); stage(2);                       // 3 tiles ahead
    for (int kt = 0; kt < nk; ++kt) {
        const int s = kt & 3;
        if (kt < nk - 2) {
            if constexpr (NI == 4) asm volatile("s_waitcnt vmcnt(8)" ::: "memory");
            else                   asm volatile("s_waitcnt vmcnt(6)" ::: "memory");
        } else if (kt == nk - 2) {
            if constexpr (NI == 4) asm volatile("s_waitcnt vmcnt(4)" ::: "memory");
            else                   asm volatile("s_waitcnt vmcnt(3)" ::: "memory");
        } else {
            asm volatile("s_waitcnt vmcnt(0)" ::: "memory");
        }
        asm volatile("s_waitcnt lgkmcnt(0)" ::: "memory");  // slot reads of kt-1 done
        asm volatile("s_barrier" ::: "memory");             // no compiler drain added
        if (kt + 3 < nk) stage(kt + 3);                     // into slot (kt-1)&3: safe

        s16x8 af[8], bf[NI];
        const int rsw = ((lo >> 1) & 3);                // f(row), row base %16 == 0
#pragma unroll
        for (int mi = 0; mi < 8; ++mi)
            af[mi] = *reinterpret_cast<const s16x8*>(
                &sm[s][0][(wm * 128 + mi * 16 + lo) * 32 + ((hi ^ rsw) * 8)]);
#pragma unroll
        for (int ni = 0; ni < NI; ++ni)
            bf[ni] = *reinterpret_cast<const s16x8*>(
                &sm[s][1][(wn * NI * 16 + ni * 16 + lo) * 32 + ((hi ^ rsw) * 8)]);
        __builtin_amdgcn_s_setprio(1);
#pragma unroll
        for (int mi = 0; mi < 8; ++mi)
#pragma unroll
            for (int ni = 0; ni < NI; ++ni)
                acc[mi][ni] = __builtin_amdgcn_mfma_f32_16x16x32_bf16(af[mi], bf[ni], acc[mi][ni], 0, 0, 0);
        __builtin_amdgcn_s_setprio(0);
    }
    const int rbase = row0 + wm * 128 + hi * 4;
    const int cbase = col0 + wn * NI * 16 + lo;
    if constexpr (BF16OUT) {
        __hip_bfloat16* C = (__hip_bfloat16*)Cv;
#pragma unroll
        for (int mi = 0; mi < 8; ++mi)
#pragma unroll
            for (int ni = 0; ni < NI; ++ni)
#pragma unroll
                for (int r = 0; r < 4; ++r)
                    C[(size_t)(rbase + mi * 16 + r) * N + cbase + ni * 16] =
                        __float2bfloat16(acc[mi][ni][r]);
    } else {
        float* C = (float*)Cv;
#pragma unroll
        for (int mi = 0; mi < 8; ++mi)
#pragma unroll
            for (int ni = 0; ni < NI; ++ni)
#pragma unroll
                for (int r = 0; r < 4; ++r)
                    C[(size_t)(rbase + mi * 16 + r) * N + cbase + ni * 16] = acc[mi][ni][r];
    }
}

// ---------------- RoPE + scatter (Q/K only, bf16 in/out, vectorized) ----------------
__global__ __launch_bounds__(256)
void rope_scatter(const __hip_bfloat16* __restrict__ qkv,
                  const float* __restrict__ cosT, const float* __restrict__ sinT,
                  __hip_bfloat16* __restrict__ Qr, __hip_bfloat16* __restrict__ Kr) {
    const int m = blockIdx.y;                           // token row, 0..4095
    const int col4 = blockIdx.x * 256 + threadIdx.x;    // 0..639
    if (col4 >= 640) return;
    const int col = col4 * 4;
    const int b = m >> 11, s = m & 2047;
    const int d = col & 127;                            // 4-aligned
    const int j = d & 63;
    union { s16x4 v4; __hip_bfloat16 h[4]; } vv, pp, u;
    vv.v4 = *reinterpret_cast<const s16x4*>(qkv + (size_t)m * 3072 + col);
    pp.v4 = *reinterpret_cast<const s16x4*>(qkv + (size_t)m * 3072 + (col ^ 64));
    const f32x4 c4 = *reinterpret_cast<const f32x4*>(cosT + s * 64 + j);
    const f32x4 s4 = *reinterpret_cast<const f32x4*>(sinT + s * 64 + j);
    const float sgn = (d < 64) ? -1.f : 1.f;
#pragma unroll
    for (int i = 0; i < 4; ++i)
        u.h[i] = __float2bfloat16(__bfloat162float(vv.h[i]) * c4[i] +
                                  sgn * __bfloat162float(pp.h[i]) * s4[i]);
    if (col < 2048) {
        const int hh = col >> 7;
        *reinterpret_cast<s16x4*>(&Qr[((size_t)(b * 16 + hh) * 2048 + s) * 128 + d]) = u.v4;
    } else {
        const int hh = (col - 2048) >> 7;
        *reinterpret_cast<s16x4*>(&Kr[((size_t)(b * 4 + hh) * 2048 + s) * 128 + d]) = u.v4;
    }
}

// ---------------- flash attention: 4 waves x 32 q-rows, 32x32 MFMA, LDS-free P ----------------
// LDS-throughput was the binding constraint (r11 analysis). This structure:
// (a) 32 q-rows/wave halves K/V fragment bytes per q; (b) swapped QK^T via
// mfma(K,Q) -> P^T: lane owns full row q = l&31 (C/D: col=l&31,
// row=(reg&3)+8*(reg>>2)+4*(l>>5), m74/m101-verified); (c) P assembled
// in-register for PV via cvt_pk + permlane32_swap (no P LDS); (d) raw
// lgkmcnt(0)+s_barrier keeps prefetch vmcnt in flight; (e) speculative exp2
// with m_run=0 init (ballot-guarded rescale off critical path; exact since
// softmax is shift-invariant and scores are far below the 2^127 exp2 range).
__global__ __launch_bounds__(256, 2)
void attn_kernel(const __hip_bfloat16* __restrict__ Qr,
                 const __hip_bfloat16* __restrict__ Kr,
                 const __hip_bfloat16* __restrict__ Vt,
                 const float* __restrict__ maskb,
                 __hip_bfloat16* __restrict__ Oo) {
    const int S = 2048;
    const int qt = blockIdx.x;                          // 0..15 (128 q-rows/block)
    const int bh = blockIdx.y;                          // 0..31
    const int b = bh >> 4, h = bh & 15, kvh = h >> 2;
    const int tid = threadIdx.x;
    const int l = tid & 63, wv_ = tid >> 6;             // 4 waves
    const int lq = l & 31, hi2 = l >> 5;
    __shared__ __align__(16) __hip_bfloat16 Ks[2][64 * 128];   // [kv][d], chunk-swizzled
    __shared__ __align__(16) __hip_bfloat16 Vs[2][128 * 64];   // [d][kv], chunk-swizzled

    const __hip_bfloat16* Qb = Qr + (size_t)(b * 16 + h) * S * 128;
    const __hip_bfloat16* Kb = Kr + (size_t)(b * 4 + kvh) * S * 128;
    const __hip_bfloat16* Vb = Vt + (size_t)(b * 4 + kvh) * 128 * S;
    const float* mrow = maskb + b * S;

    // Q fragments (B-operand): col q = lq, k = d = ks*16 + hi2*8 + j
    const int qrow = qt * 128 + wv_ * 32 + lq;
    s16x8 qf[8];
#pragma unroll
    for (int ks = 0; ks < 8; ++ks)
        qf[ks] = *reinterpret_cast<const s16x8*>(Qb + (size_t)qrow * 128 + ks * 16 + hi2 * 8);

    float m_run = 0.f, l_run = 0.f;                     // exp2-domain; row q = lq lane-local
    f32x16 o[4];                                        // O^T[dv = dt*32+...][q = lq]
#pragma unroll
    for (int dt = 0; dt < 4; ++dt)
#pragma unroll
        for (int r = 0; r < 16; ++r) o[dt][r] = 0.f;
    const float scale2 = 0.12751682f;                   // 1/sqrt(128) * log2(e)

    // staging: 256 threads; K 64x16 chunks, V 128x8 chunks, 4 each
    const int krow = tid >> 4, kc8 = tid & 15;          // rows i*16+krow
    const int koff = (kc8 ^ (krow & 7)) * 8;
    const int vrow = tid >> 3, vc8 = tid & 7;           // rows i*32+vrow
    const int voff = (vc8 ^ (vrow & 7)) * 8;

    s16x8 kreg[4], vreg[4];
    auto load_tile = [&](int kv0) {
#pragma unroll
        for (int i = 0; i < 4; ++i)
            kreg[i] = *reinterpret_cast<const s16x8*>(
                Kb + (size_t)(kv0 + i * 16 + krow) * 128 + kc8 * 8);
#pragma unroll
        for (int i = 0; i < 4; ++i)
            vreg[i] = *reinterpret_cast<const s16x8*>(
                Vb + (size_t)(i * 32 + vrow) * S + kv0 + vc8 * 8);
    };

    auto body = [&](int kt, __hip_bfloat16* Kc, __hip_bfloat16* Vc) {
        const int kv0 = kt * 64;
        // mask bias: kv = kv0 + 32*sub + 8*r4 + 4*hi2 + j
        f32x4 bi[2][4];
#pragma unroll
        for (int sub = 0; sub < 2; ++sub)
#pragma unroll
            for (int r4 = 0; r4 < 4; ++r4)
                bi[sub][r4] = *reinterpret_cast<const f32x4*>(
                    mrow + kv0 + sub * 32 + r4 * 8 + hi2 * 4);
#pragma unroll
        for (int i = 0; i < 4; ++i)
            *reinterpret_cast<s16x8*>(Kc + (i * 16 + krow) * 128 + koff) = kreg[i];
#pragma unroll
        for (int i = 0; i < 4; ++i)
            *reinterpret_cast<s16x8*>(Vc + (i * 32 + vrow) * 64 + voff) = vreg[i];
        if (kt < 31) load_tile(kv0 + 64);               // stays in flight across barrier
        asm volatile("s_waitcnt lgkmcnt(0)" ::: "memory");  // writes visible
        asm volatile("s_barrier" ::: "memory");             // NO vmcnt drain

        // P^T = K Q^T: sc[sub] covers kv-subtile sub*32, cols q
        f32x16 sc[2];
#pragma unroll
        for (int sub = 0; sub < 2; ++sub)
#pragma unroll
            for (int r = 0; r < 16; ++r) sc[sub][r] = 0.f;
        __builtin_amdgcn_s_setprio(1);
#pragma unroll
        for (int sub = 0; sub < 2; ++sub) {
            const int kr = sub * 32 + lq;
            const int ksw = kr & 7;
#pragma unroll
            for (int ks = 0; ks < 8; ++ks) {
                s16x8 kf = *reinterpret_cast<const s16x8*>(
                    Kc + kr * 128 + (((ks * 2 + hi2) ^ ksw) * 8));
                sc[sub] = __builtin_amdgcn_mfma_f32_32x32x16_bf16(kf, qf[ks], sc[sub], 0, 0, 0);
            }
        }
        __builtin_amdgcn_s_setprio(0);
        // scale + bias
#pragma unroll
        for (int sub = 0; sub < 2; ++sub)
#pragma unroll
            for (int r = 0; r < 16; ++r)
                sc[sub][r] = fmaf(sc[sub][r], scale2, bi[sub][r >> 2][r & 3]);
        // local row-max (for rare-rescale guard; off critical path)
        float mx = sc[0][0];
#pragma unroll
        for (int sub = 0; sub < 2; ++sub)
#pragma unroll
            for (int r = 0; r < 16; ++r) mx = fmaxf(mx, sc[sub][r]);
        // speculative exp2 with current m_run (likely stable at 0)
        float ss = 0.f;
#pragma unroll
        for (int sub = 0; sub < 2; ++sub)
#pragma unroll
            for (int r = 0; r < 16; ++r) {
                sc[sub][r] = fexp2(sc[sub][r] - m_run);
                ss += sc[sub][r];
            }
        mx = fmaxf(mx, __shfl_xor(mx, 32));
        if (__ballot(mx > m_run + 11.5417f) != 0ull) {  // rare: correct the speculation
            const float mnew = fmaxf(m_run, mx);
            const float alpha = fexp2(m_run - mnew);
            m_run = mnew;
            l_run *= alpha;
            ss *= alpha;
#pragma unroll
            for (int sub = 0; sub < 2; ++sub)
#pragma unroll
                for (int r = 0; r < 16; ++r) sc[sub][r] *= alpha;
#pragma unroll
            for (int dt = 0; dt < 4; ++dt)
#pragma unroll
                for (int r = 0; r < 16; ++r) o[dt][r] *= alpha;  // q lane-local
        }
        ss += __shfl_xor(ss, 32);
        l_run += ss;
        // P -> bf16 words: wvp[r4g][t] = pk(kv j=2t,2t+1) of 4-block r4g (kv=8*r4g+4*hi2)
        unsigned int wvp[8][2];
#pragma unroll
        for (int g = 0; g < 8; ++g) {
            const int sub = g >> 2, r4 = g & 3;
            asm("v_cvt_pk_bf16_f32 %0, %1, %2"
                : "=v"(wvp[g][0]) : "v"(sc[sub][r4 * 4 + 0]), "v"(sc[sub][r4 * 4 + 1]));
            asm("v_cvt_pk_bf16_f32 %0, %1, %2"
                : "=v"(wvp[g][1]) : "v"(sc[sub][r4 * 4 + 2]), "v"(sc[sub][r4 * 4 + 3]));
        }
        // O^T += V^T P^T  (A = V^T rows dv; B = P^T cols q, k = kv)
        __builtin_amdgcn_s_setprio(1);
#pragma unroll
        for (int ks = 0; ks < 4; ++ks) {
            // assemble B-frag: lane needs kv = ks*16 + hi2*8 + 0..7 packed as 4 words.
            // permlane32_swap: a.hi <-> b.lo  =>  a' = {own w[2ks] | other's w[2ks]},
            // b' = {other's w[2ks+1] ... }; per-half word order matches [a'0,a'1,b'0,b'1].
            u32x2 r0 = __builtin_amdgcn_permlane32_swap(wvp[2 * ks][0], wvp[2 * ks + 1][0], false, false);
            u32x2 r1 = __builtin_amdgcn_permlane32_swap(wvp[2 * ks][1], wvp[2 * ks + 1][1], false, false);
            union { unsigned int u[4]; s16x8 v; } pf;
            pf.u[0] = r0.x; pf.u[1] = r1.x; pf.u[2] = r0.y; pf.u[3] = r1.y;
#pragma unroll
            for (int dt = 0; dt < 4; ++dt) {
                const int dvr = dt * 32 + lq;
                s16x8 vf = *reinterpret_cast<const s16x8*>(
                    Vc + dvr * 64 + (((ks * 2 + hi2) ^ (dvr & 7)) * 8));
                o[dt] = __builtin_amdgcn_mfma_f32_32x32x16_bf16(vf, pf.v, o[dt], 0, 0, 0);
            }
        }
        __builtin_amdgcn_s_setprio(0);
    };

    load_tile(0);
    for (int kt2 = 0; kt2 < 16; ++kt2) {                // x2 unroll: static LDS bases
        body(2 * kt2,     &Ks[0][0], &Vs[0][0]);
        body(2 * kt2 + 1, &Ks[1][0], &Vs[1][0]);
    }
    // epilogue: Oo[s][h*128 + dv] = o / l; q = lq lane-local, dv = dt*32+8*r4+4*hi2+j
    const float inv = 1.f / l_run;
    const size_t obase = (size_t)(b * S + qt * 128 + wv_ * 32 + lq) * 2048 + h * 128;
#pragma unroll
    for (int dt = 0; dt < 4; ++dt)
#pragma unroll
        for (int r4 = 0; r4 < 4; ++r4) {
            union { s16x4 v4; __hip_bfloat16 hh[4]; } u;
#pragma unroll
            for (int j = 0; j < 4; ++j)
                u.hh[j] = __float2bfloat16(o[dt][r4 * 4 + j] * inv);
            *reinterpret_cast<s16x4*>(&Oo[obase + dt * 32 + r4 * 8 + hi2 * 4]) = u.v4;
        }
}

// ---------------- host launch ----------------
extern "C" void kernel_launch(void* const* d_in, const int* in_sizes, int n_in,
                              void* d_out, int out_size, void* d_ws, size_t ws_size,
                              hipStream_t stream) {
    const float* x  = (const float*)d_in[0];
    const int* mask = (const int*)d_in[1];
    const float* Wq = (const float*)d_in[2];
    const float* Wk = (const float*)d_in[3];
    const float* Wv = (const float*)d_in[4];
    const float* Wo = (const float*)d_in[5];
    float* out = (float*)d_out;

    char* ws = (char*)d_ws;
    size_t off = 0;
    auto alloc = [&](size_t bytes) -> void* {
        void* p = ws + off;
        off += (bytes + 255) & ~(size_t)255;
        return p;
    };
    __hip_bfloat16* xb     = (__hip_bfloat16*)alloc(4096ULL * 2048 * 2);   // 16 MB
    __hip_bfloat16* wqkv_t = (__hip_bfloat16*)alloc(3072ULL * 2048 * 2);   // 12 MB
    __hip_bfloat16* wo_t   = (__hip_bfloat16*)alloc(2048ULL * 2048 * 2);   // 8 MB
    __hip_bfloat16* qkvb   = (__hip_bfloat16*)alloc(4096ULL * 3072 * 2);   // 24 MB
    __hip_bfloat16* Kr     = (__hip_bfloat16*)alloc(2ULL * 4 * 2048 * 128 * 2);  // 4 MB
    __hip_bfloat16* Vt     = (__hip_bfloat16*)alloc(2ULL * 4 * 2048 * 128 * 2);  // 4 MB
    float*          cosT   = (float*)alloc(2048ULL * 64 * 4);
    float*          sinT   = (float*)alloc(2048ULL * 64 * 4);
    float*          maskb  = (float*)alloc(2ULL * 2048 * 4);
    __hip_bfloat16* attno  = (__hip_bfloat16*)alloc(4096ULL * 2048 * 2);   // 16 MB
    __hip_bfloat16* Qr    = xb;   // xb dead after QKV GEMM; Qr written after

    rope_tables<<<dim3(2048), dim3(64), 0, stream>>>(cosT, sinT);
    mask_bias<<<dim3(16), dim3(256), 0, stream>>>(mask, maskb, 4096);
    cast_f32_bf16<<<dim3(8192), dim3(256), 0, stream>>>(x, xb, 2097152);
    transpose_cast<<<dim3(64, 64), dim3(32, 8), 0, stream>>>(Wq, wqkv_t, 2048, 2048);
    transpose_cast<<<dim3(16, 64), dim3(32, 8), 0, stream>>>(Wk, wqkv_t + 2048ULL * 2048, 2048, 512);
    transpose_cast<<<dim3(16, 64), dim3(32, 8), 0, stream>>>(Wv, wqkv_t + 2560ULL * 2048, 2048, 512);
    transpose_cast<<<dim3(64, 64), dim3(32, 8), 0, stream>>>(Wo, wo_t, 2048, 2048);

    // QKV: 256x256 tiles, 1-D grid 192 (NX=12, NY=16), bf16 output
    gemm256_bt<4, true><<<dim3(192), dim3(512), 0, stream>>>(xb, wqkv_t, qkvb, 4096, 3072, 2048, 12);
    rope_scatter<<<dim3(3, 4096), dim3(256), 0, stream>>>(qkvb, cosT, sinT, Qr, Kr);
    vt_transpose<<<dim3(64, 4, 8), dim3(32, 8), 0, stream>>>(qkvb, Vt);
    attn_kernel<<<dim3(16, 32), dim3(256), 0, stream>>>(Qr, Kr, Vt, maskb, attno);
    // Wo: 256x128 tiles, 1-D grid 256 (NX=16, NY=16), fp32 output
    gemm256_bt<2, false><<<dim3(256), dim3(512), 0, stream>>>(attno, wo_t, out, 4096, 2048, 2048, 16);
}